// Round 5
// baseline (295.882 us; speedup 1.0000x reference)
//
#include <hip/hip_runtime.h>
#include <hip/hip_bf16.h>

using bf16 = __hip_bfloat16;
typedef __attribute__((ext_vector_type(8))) __bf16 bf16x8;
typedef __attribute__((ext_vector_type(4))) float f32x4;
typedef __attribute__((ext_vector_type(16))) float f32x16;

#define MFMA16(a, b, c) __builtin_amdgcn_mfma_f32_16x16x32_bf16((a), (b), (c), 0, 0, 0)
#define MFMA32(a, b, c) __builtin_amdgcn_mfma_f32_32x32x16_bf16((a), (b), (c), 0, 0, 0)

static __device__ __forceinline__ void gload_lds16(const bf16* g, bf16* l) {
    __builtin_amdgcn_global_load_lds(
        (__attribute__((address_space(1))) void*)(bf16*)(g),
        (__attribute__((address_space(3))) void*)(l), 16, 0, 0);
}

static __device__ __forceinline__ unsigned cvtpk(float lo, float hi) {
    unsigned r;
    asm("v_cvt_pk_bf16_f32 %0, %1, %2" : "=v"(r) : "v"(lo), "v"(hi));
    return r;
}

// ---------------------------------------------------------------- convert
__global__ void cvt_f32_bf16(const float* __restrict__ in, bf16* __restrict__ out, int n4) {
    int i = blockIdx.x * 256 + threadIdx.x;
    if (i >= n4) return;
    float4 v = ((const float4*)in)[i];
    bf16 t[4];
    t[0] = __float2bfloat16(v.x);
    t[1] = __float2bfloat16(v.y);
    t[2] = __float2bfloat16(v.z);
    t[3] = __float2bfloat16(v.w);
    *(uint2*)(out + 4l * i) = *(uint2*)t;
}

// ---------------------------------------------------------------- GEMM1: qkv = x @ Wqkv^T + b, scatter to Q,K,V^T (bf16)
__global__ void gemm_qkv(const bf16* __restrict__ A, const bf16* __restrict__ B,
                         const float* __restrict__ bias,
                         bf16* __restrict__ Qo, bf16* __restrict__ Ko, bf16* __restrict__ Vt) {
    const int K = 1024;
    __shared__ bf16 Alds[128 * 32];
    __shared__ bf16 Blds[128 * 32];
    int t = threadIdx.x;
    int lane = t & 63;
    int wave = t >> 6;
    int wm = wave >> 1, wn = wave & 1;
    int r = lane & 15, q = lane >> 4;
    long m0 = (long)blockIdx.y * 128;
    long n0 = (long)blockIdx.x * 128;
    const bf16* Ab = A + m0 * K;
    const bf16* Bb = B + n0 * K;

    f32x4 acc[4][4] = {};

    int srow = t >> 2;
    int scol = (t & 3) << 3;

    for (int k0 = 0; k0 < K; k0 += 32) {
        __syncthreads();
        gload_lds16(Ab + (long)srow * K + k0 + scol, Alds + t * 8);
        gload_lds16(Ab + (long)(srow + 64) * K + k0 + scol, Alds + 2048 + t * 8);
        gload_lds16(Bb + (long)srow * K + k0 + scol, Blds + t * 8);
        gload_lds16(Bb + (long)(srow + 64) * K + k0 + scol, Blds + 2048 + t * 8);
        __syncthreads();

        bf16x8 af[4], bfv[4];
#pragma unroll
        for (int mi = 0; mi < 4; mi++)
            af[mi] = *(const bf16x8*)(Alds + (wm * 64 + mi * 16 + r) * 32 + q * 8);
#pragma unroll
        for (int ni = 0; ni < 4; ni++)
            bfv[ni] = *(const bf16x8*)(Blds + (wn * 64 + ni * 16 + r) * 32 + q * 8);
#pragma unroll
        for (int mi = 0; mi < 4; mi++)
#pragma unroll
            for (int ni = 0; ni < 4; ni++)
                acc[mi][ni] = MFMA16(af[mi], bfv[ni], acc[mi][ni]);
    }

#pragma unroll
    for (int ni = 0; ni < 4; ni++) {
        int n = (int)n0 + wn * 64 + ni * 16 + r;
        float bn = bias[n];
        int h = n / 192;
        int rem = n % 192;
        int part = rem >> 6;
        int d = rem & 63;
#pragma unroll
        for (int mi = 0; mi < 4; mi++) {
#pragma unroll
            for (int rr = 0; rr < 4; rr++) {
                int m = (int)m0 + wm * 64 + mi * 16 + q * 4 + rr;
                int b = m >> 11;
                int row = m & 2047;
                long bh = b * 16 + h;
                bf16 bv = __float2bfloat16(acc[mi][ni][rr] + bn);
                if (part == 0)      Qo[(bh * 2048 + row) * 64 + d] = bv;
                else if (part == 1) Ko[(bh * 2048 + row) * 64 + d] = bv;
                else                Vt[(bh * 64 + d) * 2048 + row] = bv;
            }
        }
    }
}

// ---------------------------------------------------------------- attention
// 32x32 MFMA, swapped QK^T (S^T), in-register P, O^T accumulation, defer-max.
// Block: 4 waves x 32 q-rows = 128 q; KVBLK = 64; frag-linear LDS (0 conflicts).
// Grid: 1024 blocks (4/CU), XCD-swizzled so each XCD owns 8 bh (K/V fits its L2).
union PU { unsigned u[4]; bf16x8 v; };

#define PACK8(S, OFF, F) { \
    unsigned A0 = cvtpk(S[OFF+0], S[OFF+1]); \
    unsigned B0 = cvtpk(S[OFF+4], S[OFF+5]); \
    unsigned A1 = cvtpk(S[OFF+2], S[OFF+3]); \
    unsigned B1 = cvtpk(S[OFF+6], S[OFF+7]); \
    unsigned snd0 = hi ? A0 : B0; unsigned got0 = (unsigned)__shfl_xor((int)snd0, 32); \
    unsigned snd1 = hi ? A1 : B1; unsigned got1 = (unsigned)__shfl_xor((int)snd1, 32); \
    F.u[0] = hi ? got0 : A0; F.u[2] = hi ? B0 : got0; \
    F.u[1] = hi ? got1 : A1; F.u[3] = hi ? B1 : got1; }

__global__ __launch_bounds__(256, 4) void attn_fwd(const bf16* __restrict__ Q,
                                                   const bf16* __restrict__ Kg,
                                                   const bf16* __restrict__ Vt,
                                                   bf16* __restrict__ AO) {
    __shared__ bf16 smem[8192];   // K frags [0..4095], V frags [4096..8191]
    bf16* Ksh = smem;
    bf16* Vsh = smem + 4096;
    const int t = threadIdx.x;
    const int lane = t & 63, wave = t >> 6;
    const int l31 = lane & 31, hi = lane >> 5;
    // XCD swizzle: 1024 blocks, xcd = bid&7 owns bh in [xcd*8, xcd*8+8)
    const int bid = blockIdx.x;
    const int xcd = bid & 7, idx = bid >> 3;
    const int bh = xcd * 8 + (idx >> 4);
    const int qt = idx & 15;
    const float C1 = 0.18033688011112042f;   // log2(e)/sqrt(64)

    // Q fragments in registers all kernel
    bf16x8 qf[4];
    {
        const bf16* Qb = Q + ((long)bh * 2048 + qt * 128 + wave * 32 + l31) * 64 + hi * 8;
#pragma unroll
        for (int k0 = 0; k0 < 4; ++k0)
            qf[k0] = *(const bf16x8*)(Qb + k0 * 16);
    }

    const bf16* Kh = Kg + (long)bh * 2048 * 64;
    const bf16* Vh = Vt + (long)bh * 64 * 2048;

    // O^T accumulators (col = q = l31), m/l lane-local
    f32x16 o0 = {}, o1 = {};
    float mv = -1e30f, lv = 0.f;

    // async staging regs (frag-linear slots: slot = c*256 + t)
    int4 kr[2], vr[2];
    auto stage_load = [&](int kv0) {
#pragma unroll
        for (int c = 0; c < 2; ++c) {
            kr[c] = *(const int4*)(Kh + (long)(kv0 + c * 32 + l31) * 64 + wave * 16 + hi * 8);
            vr[c] = *(const int4*)(Vh + (long)(c * 32 + l31) * 2048 + kv0 + wave * 16 + hi * 8);
        }
    };
    auto stage_write = [&]() {
#pragma unroll
        for (int c = 0; c < 2; ++c) {
            *(int4*)(Ksh + ((c << 8) + t) * 8) = kr[c];
            *(int4*)(Vsh + ((c << 8) + t) * 8) = vr[c];
        }
    };

    stage_load(0);
    stage_write();
    stage_load(64);
    __syncthreads();

    for (int kv0 = 0;; kv0 += 64) {
        // ---- S^T = K·Q^T (frag-linear K reads, 0 conflicts)
        f32x16 sA = {}, sB = {};
        __builtin_amdgcn_s_setprio(1);
#pragma unroll
        for (int k0 = 0; k0 < 4; ++k0) {
            bf16x8 kfA = *(const bf16x8*)(Ksh + (k0 * 64 + lane) * 8);
            bf16x8 kfB = *(const bf16x8*)(Ksh + (256 + k0 * 64 + lane) * 8);
            sA = MFMA32(kfA, qf[k0], sA);
            sB = MFMA32(kfB, qf[k0], sB);
        }
        __builtin_amdgcn_s_setprio(0);

        // ---- lane-local softmax with defer-max (THR=8 raw-logit)
        float x0 = fmaxf(fmaxf(sA[0], sA[1]), fmaxf(sA[2], sA[3]));
        float x1 = fmaxf(fmaxf(sA[4], sA[5]), fmaxf(sA[6], sA[7]));
        float x2 = fmaxf(fmaxf(sA[8], sA[9]), fmaxf(sA[10], sA[11]));
        float x3 = fmaxf(fmaxf(sA[12], sA[13]), fmaxf(sA[14], sA[15]));
        float y0 = fmaxf(fmaxf(sB[0], sB[1]), fmaxf(sB[2], sB[3]));
        float y1 = fmaxf(fmaxf(sB[4], sB[5]), fmaxf(sB[6], sB[7]));
        float y2 = fmaxf(fmaxf(sB[8], sB[9]), fmaxf(sB[10], sB[11]));
        float y3 = fmaxf(fmaxf(sB[12], sB[13]), fmaxf(sB[14], sB[15]));
        float pm = fmaxf(fmaxf(fmaxf(x0, x1), fmaxf(x2, x3)),
                         fmaxf(fmaxf(y0, y1), fmaxf(y2, y3)));
        pm = fmaxf(pm, __shfl_xor(pm, 32));
        bool resc = !__all(pm <= mv + 8.0f);
        float al = 1.f;
        if (resc) {
            float mn = fmaxf(mv, pm);
            al = exp2f((mv - mn) * C1);
            mv = mn;
        }
        float mc = mv * C1;
        float ts = 0.f;
#pragma unroll
        for (int e = 0; e < 16; ++e) { float p = exp2f(sA[e] * C1 - mc); sA[e] = p; ts += p; }
#pragma unroll
        for (int e = 0; e < 16; ++e) { float p = exp2f(sB[e] * C1 - mc); sB[e] = p; ts += p; }
        ts += __shfl_xor(ts, 32);
        if (resc) {
            lv = lv * al + ts;
#pragma unroll
            for (int e = 0; e < 16; ++e) { o0[e] *= al; o1[e] *= al; }
        } else {
            lv += ts;
        }

        // ---- pack P into PV B-fragments (in-register, cross-half exchange)
        PU f[4];
        PACK8(sA, 0, f[0]);
        PACK8(sA, 8, f[1]);
        PACK8(sB, 0, f[2]);
        PACK8(sB, 8, f[3]);

        // ---- O^T += V^T·P (frag-linear V reads, 0 conflicts)
        __builtin_amdgcn_s_setprio(1);
#pragma unroll
        for (int kf = 0; kf < 4; ++kf) {
            bf16x8 vfA = *(const bf16x8*)(Vsh + (kf * 64 + lane) * 8);
            bf16x8 vfB = *(const bf16x8*)(Vsh + (256 + kf * 64 + lane) * 8);
            o0 = MFMA32(vfA, f[kf].v, o0);
            o1 = MFMA32(vfB, f[kf].v, o1);
        }
        __builtin_amdgcn_s_setprio(0);

        if (kv0 == 2048 - 64) break;
        __syncthreads();
        stage_write();                       // tile kv0+64 from regs
        if (kv0 + 128 < 2048) stage_load(kv0 + 128);
        __syncthreads();
    }

    // ---- epilogue: O^T -> LDS transpose -> coalesced global stores
    long b = bh >> 4, h = bh & 15;
    __syncthreads();
    float il = 1.f / lv;
    char* wbase = (char*)smem + wave * 4096 + l31 * 128;
#pragma unroll
    for (int ds = 0; ds < 2; ++ds) {
        const f32x16& E = ds ? o1 : o0;
#pragma unroll
        for (int j = 0; j < 4; ++j) {
            unsigned wlo = cvtpk(E[4 * j] * il, E[4 * j + 1] * il);
            unsigned whi = cvtpk(E[4 * j + 2] * il, E[4 * j + 3] * il);
            int b8 = ds * 8 + 2 * j + hi;
            int b8s = b8 ^ ((l31 & 7) << 1);
            uint2 val; val.x = wlo; val.y = whi;
            *(uint2*)(wbase + b8s * 8) = val;
        }
    }
    __syncthreads();
    int rid = t >> 1, hf = t & 1;
    int wv = rid >> 5, qq = rid & 31;
    long orow = (long)qt * 128 + wv * 32 + qq;
    const char* rbase = (const char*)smem + wv * 4096 + qq * 128;
    bf16* dst = AO + (b * 2048 + orow) * 1024 + h * 64 + hf * 32;
#pragma unroll
    for (int k = 0; k < 4; ++k) {
        int b8 = hf * 8 + 2 * k;
        int b8s = b8 ^ ((qq & 7) << 1);
        int4 v = *(const int4*)(rbase + b8s * 8);
        *(int4*)(dst + k * 8) = v;
    }
}

// ---------------------------------------------------------------- GEMM2: out = AO @ Wo^T + bo (fp32 out)
__global__ void gemm_out(const bf16* __restrict__ A, const bf16* __restrict__ B,
                         const float* __restrict__ bias, float* __restrict__ C) {
    const int K = 1024, N = 1024;
    __shared__ bf16 Alds[128 * 32];
    __shared__ bf16 Blds[128 * 32];
    int t = threadIdx.x;
    int lane = t & 63;
    int wave = t >> 6;
    int wm = wave >> 1, wn = wave & 1;
    int r = lane & 15, q = lane >> 4;
    long m0 = (long)blockIdx.y * 128;
    long n0 = (long)blockIdx.x * 128;
    const bf16* Ab = A + m0 * K;
    const bf16* Bb = B + n0 * K;

    f32x4 acc[4][4] = {};

    int srow = t >> 2;
    int scol = (t & 3) << 3;

    for (int k0 = 0; k0 < K; k0 += 32) {
        __syncthreads();
        gload_lds16(Ab + (long)srow * K + k0 + scol, Alds + t * 8);
        gload_lds16(Ab + (long)(srow + 64) * K + k0 + scol, Alds + 2048 + t * 8);
        gload_lds16(Bb + (long)srow * K + k0 + scol, Blds + t * 8);
        gload_lds16(Bb + (long)(srow + 64) * K + k0 + scol, Blds + 2048 + t * 8);
        __syncthreads();

        bf16x8 af[4], bfv[4];
#pragma unroll
        for (int mi = 0; mi < 4; mi++)
            af[mi] = *(const bf16x8*)(Alds + (wm * 64 + mi * 16 + r) * 32 + q * 8);
#pragma unroll
        for (int ni = 0; ni < 4; ni++)
            bfv[ni] = *(const bf16x8*)(Blds + (wn * 64 + ni * 16 + r) * 32 + q * 8);
#pragma unroll
        for (int mi = 0; mi < 4; mi++)
#pragma unroll
            for (int ni = 0; ni < 4; ni++)
                acc[mi][ni] = MFMA16(af[mi], bfv[ni], acc[mi][ni]);
    }

#pragma unroll
    for (int ni = 0; ni < 4; ni++) {
        int n = (int)n0 + wn * 64 + ni * 16 + r;
        float bn = bias[n];
#pragma unroll
        for (int mi = 0; mi < 4; mi++) {
#pragma unroll
            for (int rr = 0; rr < 4; rr++) {
                long m = m0 + wm * 64 + mi * 16 + q * 4 + rr;
                C[m * N + n] = acc[mi][ni][rr] + bn;
            }
        }
    }
}

// ---------------------------------------------------------------- launch
extern "C" void kernel_launch(void* const* d_in, const int* in_sizes, int n_in,
                              void* d_out, int out_size, void* d_ws, size_t ws_size,
                              hipStream_t stream) {
    const float* x    = (const float*)d_in[0];
    const float* Wqkv = (const float*)d_in[1];
    const float* bqkv = (const float*)d_in[2];
    const float* Wo   = (const float*)d_in[3];
    const float* bo   = (const float*)d_in[4];
    float* out = (float*)d_out;

    char* ws = (char*)d_ws;
    bf16* Xb  = (bf16*)(ws + 0);
    bf16* Wqb = (bf16*)(ws + 16777216);
    bf16* Wob = (bf16*)(ws + 23068672);
    bf16* Qb  = (bf16*)(ws + 25165824);
    bf16* Kb  = (bf16*)(ws + 41943040);
    bf16* Vtb = (bf16*)(ws + 58720256);
    bf16* AOb = (bf16*)(ws + 75497472);

    cvt_f32_bf16<<<8192, 256, 0, stream>>>(x, Xb, 8192 * 1024 / 4);
    cvt_f32_bf16<<<3072, 256, 0, stream>>>(Wqkv, Wqb, 3072 * 1024 / 4);
    cvt_f32_bf16<<<1024, 256, 0, stream>>>(Wo, Wob, 1024 * 1024 / 4);

    gemm_qkv<<<dim3(24, 64), 256, 0, stream>>>(Xb, Wqb, bqkv, Qb, Kb, Vtb);
    attn_fwd<<<1024, 256, 0, stream>>>(Qb, Kb, Vtb, AOb);
    gemm_out<<<dim3(8, 64), 256, 0, stream>>>(AOb, Wob, bo, out);
}

// Round 6
// 251.964 us; speedup vs baseline: 1.1743x; 1.1743x over previous
//
#include <hip/hip_runtime.h>
#include <hip/hip_bf16.h>

using bf16 = __hip_bfloat16;
typedef __attribute__((ext_vector_type(8))) __bf16 bf16x8;
typedef __attribute__((ext_vector_type(4))) float f32x4;
typedef __attribute__((ext_vector_type(16))) float f32x16;
typedef __attribute__((ext_vector_type(4))) unsigned u32x4;

#define MFMA16(a, b, c) __builtin_amdgcn_mfma_f32_16x16x32_bf16((a), (b), (c), 0, 0, 0)
#define MFMA32(a, b, c) __builtin_amdgcn_mfma_f32_32x32x16_bf16((a), (b), (c), 0, 0, 0)

static __device__ __forceinline__ void gload_lds16(const bf16* g, bf16* l) {
    __builtin_amdgcn_global_load_lds(
        (__attribute__((address_space(1))) void*)(bf16*)(g),
        (__attribute__((address_space(3))) void*)(l), 16, 0, 0);
}

static __device__ __forceinline__ unsigned cvtpk(float lo, float hi) {
    unsigned r;
    asm("v_cvt_pk_bf16_f32 %0, %1, %2" : "=v"(r) : "v"(lo), "v"(hi));
    return r;
}

// ---------------------------------------------------------------- convert
__global__ void cvt_f32_bf16(const float* __restrict__ in, bf16* __restrict__ out, int n4) {
    int i = blockIdx.x * 256 + threadIdx.x;
    if (i >= n4) return;
    float4 v = ((const float4*)in)[i];
    bf16 t[4];
    t[0] = __float2bfloat16(v.x);
    t[1] = __float2bfloat16(v.y);
    t[2] = __float2bfloat16(v.z);
    t[3] = __float2bfloat16(v.w);
    *(uint2*)(out + 4l * i) = *(uint2*)t;
}

// ---------------------------------------------------------------- GEMM1: qkv = x @ Wqkv^T + b, scatter to Q,K,V^T (bf16)
__global__ void gemm_qkv(const bf16* __restrict__ A, const bf16* __restrict__ B,
                         const float* __restrict__ bias,
                         bf16* __restrict__ Qo, bf16* __restrict__ Ko, bf16* __restrict__ Vt) {
    const int K = 1024;
    __shared__ bf16 Alds[128 * 32];
    __shared__ bf16 Blds[128 * 32];
    int t = threadIdx.x;
    int lane = t & 63;
    int wave = t >> 6;
    int wm = wave >> 1, wn = wave & 1;
    int r = lane & 15, q = lane >> 4;
    long m0 = (long)blockIdx.y * 128;
    long n0 = (long)blockIdx.x * 128;
    const bf16* Ab = A + m0 * K;
    const bf16* Bb = B + n0 * K;

    f32x4 acc[4][4] = {};

    int srow = t >> 2;
    int scol = (t & 3) << 3;

    for (int k0 = 0; k0 < K; k0 += 32) {
        __syncthreads();
        gload_lds16(Ab + (long)srow * K + k0 + scol, Alds + t * 8);
        gload_lds16(Ab + (long)(srow + 64) * K + k0 + scol, Alds + 2048 + t * 8);
        gload_lds16(Bb + (long)srow * K + k0 + scol, Blds + t * 8);
        gload_lds16(Bb + (long)(srow + 64) * K + k0 + scol, Blds + 2048 + t * 8);
        __syncthreads();

        bf16x8 af[4], bfv[4];
#pragma unroll
        for (int mi = 0; mi < 4; mi++)
            af[mi] = *(const bf16x8*)(Alds + (wm * 64 + mi * 16 + r) * 32 + q * 8);
#pragma unroll
        for (int ni = 0; ni < 4; ni++)
            bfv[ni] = *(const bf16x8*)(Blds + (wn * 64 + ni * 16 + r) * 32 + q * 8);
#pragma unroll
        for (int mi = 0; mi < 4; mi++)
#pragma unroll
            for (int ni = 0; ni < 4; ni++)
                acc[mi][ni] = MFMA16(af[mi], bfv[ni], acc[mi][ni]);
    }

#pragma unroll
    for (int ni = 0; ni < 4; ni++) {
        int n = (int)n0 + wn * 64 + ni * 16 + r;
        float bn = bias[n];
        int h = n / 192;
        int rem = n % 192;
        int part = rem >> 6;
        int d = rem & 63;
#pragma unroll
        for (int mi = 0; mi < 4; mi++) {
#pragma unroll
            for (int rr = 0; rr < 4; rr++) {
                int m = (int)m0 + wm * 64 + mi * 16 + q * 4 + rr;
                int b = m >> 11;
                int row = m & 2047;
                long bh = b * 16 + h;
                bf16 bv = __float2bfloat16(acc[mi][ni][rr] + bn);
                if (part == 0)      Qo[(bh * 2048 + row) * 64 + d] = bv;
                else if (part == 1) Ko[(bh * 2048 + row) * 64 + d] = bv;
                else                Vt[(bh * 64 + d) * 2048 + row] = bv;
            }
        }
    }
}

// ---------------------------------------------------------------- attention
// 32x32 MFMA, swapped QK^T (S^T), in-register P, O^T accumulation, defer-max.
// Block: 4 waves x 64 q (2 interleaved q-blocks); 512 blocks XCD-swizzled.
// All hot-path state in NAMED registers (no arrays/unions -> no scratch).

#define PACK8(S, OFF, OUTV) { \
    unsigned A0 = cvtpk(S[OFF+0], S[OFF+1]); \
    unsigned B0 = cvtpk(S[OFF+4], S[OFF+5]); \
    unsigned A1 = cvtpk(S[OFF+2], S[OFF+3]); \
    unsigned B1 = cvtpk(S[OFF+6], S[OFF+7]); \
    unsigned snd0 = hi ? A0 : B0; unsigned got0 = (unsigned)__shfl_xor((int)snd0, 32); \
    unsigned snd1 = hi ? A1 : B1; unsigned got1 = (unsigned)__shfl_xor((int)snd1, 32); \
    u32x4 W; \
    W.x = hi ? got0 : A0; W.z = hi ? B0 : got0; \
    W.y = hi ? got1 : A1; W.w = hi ? B1 : got1; \
    OUTV = __builtin_bit_cast(bf16x8, W); }

#define QKT(QF0, QF1, QF2, QF3, SA, SB) { \
    bf16x8 kA, kB; \
    kA = *(const bf16x8*)(Ksh + (0 * 64 + lane) * 8); \
    kB = *(const bf16x8*)(Ksh + (256 + 0 * 64 + lane) * 8); \
    SA = MFMA32(kA, QF0, SA);  SB = MFMA32(kB, QF0, SB); \
    kA = *(const bf16x8*)(Ksh + (1 * 64 + lane) * 8); \
    kB = *(const bf16x8*)(Ksh + (256 + 1 * 64 + lane) * 8); \
    SA = MFMA32(kA, QF1, SA);  SB = MFMA32(kB, QF1, SB); \
    kA = *(const bf16x8*)(Ksh + (2 * 64 + lane) * 8); \
    kB = *(const bf16x8*)(Ksh + (256 + 2 * 64 + lane) * 8); \
    SA = MFMA32(kA, QF2, SA);  SB = MFMA32(kB, QF2, SB); \
    kA = *(const bf16x8*)(Ksh + (3 * 64 + lane) * 8); \
    kB = *(const bf16x8*)(Ksh + (256 + 3 * 64 + lane) * 8); \
    SA = MFMA32(kA, QF3, SA);  SB = MFMA32(kB, QF3, SB); }

#define PVSTEP(KF, PF, O0, O1) { \
    bf16x8 vA = *(const bf16x8*)(Vsh + (KF * 64 + lane) * 8); \
    bf16x8 vB = *(const bf16x8*)(Vsh + (256 + KF * 64 + lane) * 8); \
    O0 = MFMA32(vA, PF, O0); \
    O1 = MFMA32(vB, PF, O1); }

#define SOFTMAX_PV(SA, SB, O0, O1, MV, LV) do { \
    float x0 = fmaxf(fmaxf(SA[0], SA[1]), fmaxf(SA[2], SA[3])); \
    float x1 = fmaxf(fmaxf(SA[4], SA[5]), fmaxf(SA[6], SA[7])); \
    float x2 = fmaxf(fmaxf(SA[8], SA[9]), fmaxf(SA[10], SA[11])); \
    float x3 = fmaxf(fmaxf(SA[12], SA[13]), fmaxf(SA[14], SA[15])); \
    float y0 = fmaxf(fmaxf(SB[0], SB[1]), fmaxf(SB[2], SB[3])); \
    float y1 = fmaxf(fmaxf(SB[4], SB[5]), fmaxf(SB[6], SB[7])); \
    float y2 = fmaxf(fmaxf(SB[8], SB[9]), fmaxf(SB[10], SB[11])); \
    float y3 = fmaxf(fmaxf(SB[12], SB[13]), fmaxf(SB[14], SB[15])); \
    float pm = fmaxf(fmaxf(fmaxf(x0, x1), fmaxf(x2, x3)), \
                     fmaxf(fmaxf(y0, y1), fmaxf(y2, y3))); \
    pm = fmaxf(pm, __shfl_xor(pm, 32)); \
    bool resc = !__all(pm <= MV + 8.0f); \
    float al = 1.f; \
    if (resc) { float mn = fmaxf(MV, pm); al = exp2f((MV - mn) * C1); MV = mn; } \
    float mc = MV * C1; \
    float ts = 0.f; \
    _Pragma("unroll") for (int e = 0; e < 16; ++e) { float p = exp2f(SA[e] * C1 - mc); SA[e] = p; ts += p; } \
    _Pragma("unroll") for (int e = 0; e < 16; ++e) { float p = exp2f(SB[e] * C1 - mc); SB[e] = p; ts += p; } \
    ts += __shfl_xor(ts, 32); \
    if (resc) { \
        LV = LV * al + ts; \
        _Pragma("unroll") for (int e = 0; e < 16; ++e) { O0[e] *= al; O1[e] *= al; } \
    } else { LV += ts; } \
    bf16x8 pf0, pf1, pf2, pf3; \
    PACK8(SA, 0, pf0); PACK8(SA, 8, pf1); PACK8(SB, 0, pf2); PACK8(SB, 8, pf3); \
    __builtin_amdgcn_s_setprio(1); \
    PVSTEP(0, pf0, O0, O1); \
    PVSTEP(1, pf1, O0, O1); \
    PVSTEP(2, pf2, O0, O1); \
    PVSTEP(3, pf3, O0, O1); \
    __builtin_amdgcn_s_setprio(0); \
} while (0)

#define EPI(O0v, O1v, LVv, QBOFF) { \
    __syncthreads(); \
    float il = 1.f / LVv; \
    char* wbase = (char*)smem + wave * 4096 + l31 * 128; \
    _Pragma("unroll") for (int j = 0; j < 4; ++j) { \
        unsigned wlo = cvtpk(O0v[4 * j] * il, O0v[4 * j + 1] * il); \
        unsigned whi = cvtpk(O0v[4 * j + 2] * il, O0v[4 * j + 3] * il); \
        int b8 = 2 * j + hi; int b8s = b8 ^ ((l31 & 7) << 1); \
        uint2 val; val.x = wlo; val.y = whi; \
        *(uint2*)(wbase + b8s * 8) = val; } \
    _Pragma("unroll") for (int j = 0; j < 4; ++j) { \
        unsigned wlo = cvtpk(O1v[4 * j] * il, O1v[4 * j + 1] * il); \
        unsigned whi = cvtpk(O1v[4 * j + 2] * il, O1v[4 * j + 3] * il); \
        int b8 = 8 + 2 * j + hi; int b8s = b8 ^ ((l31 & 7) << 1); \
        uint2 val; val.x = wlo; val.y = whi; \
        *(uint2*)(wbase + b8s * 8) = val; } \
    __syncthreads(); \
    { int rid = t >> 1, hf = t & 1; \
      int wv = rid >> 5, qq = rid & 31; \
      long orow = (long)qt * 256 + wv * 64 + (QBOFF) + qq; \
      const char* rbase = (const char*)smem + wv * 4096 + qq * 128; \
      bf16* dst = AO + (bb * 2048 + orow) * 1024 + hh * 64 + hf * 32; \
      _Pragma("unroll") for (int k = 0; k < 4; ++k) { \
          int b8 = hf * 8 + 2 * k; int b8s = b8 ^ ((qq & 7) << 1); \
          int4 v = *(const int4*)(rbase + b8s * 8); \
          *(int4*)(dst + k * 8) = v; } } }

__global__ __launch_bounds__(256, 2) void attn_fwd(const bf16* __restrict__ Q,
                                                   const bf16* __restrict__ Kg,
                                                   const bf16* __restrict__ Vt,
                                                   bf16* __restrict__ AO) {
    __shared__ bf16 smem[8192];   // K frags [0..4095], V frags [4096..8191]
    bf16* Ksh = smem;
    bf16* Vsh = smem + 4096;
    const int t = threadIdx.x;
    const int lane = t & 63, wave = t >> 6;
    const int l31 = lane & 31, hi = lane >> 5;
    // XCD swizzle: 512 blocks; xcd = bid&7 owns bh in [xcd*8, xcd*8+8)
    const int bid = blockIdx.x;
    const int xcd = bid & 7, idx = bid >> 3;
    const int bh = xcd * 8 + (idx >> 3);
    const int qt = idx & 7;
    const float C1 = 0.18033688011112042f;   // log2(e)/sqrt(64)

    // Q fragments in registers all kernel (2 q-blocks x 4 k-chunks), all named
    bf16x8 qf00, qf01, qf02, qf03, qf10, qf11, qf12, qf13;
    {
        const bf16* Qb = Q + ((long)bh * 2048 + qt * 256 + wave * 64 + l31) * 64 + hi * 8;
        qf00 = *(const bf16x8*)(Qb + 0);
        qf01 = *(const bf16x8*)(Qb + 16);
        qf02 = *(const bf16x8*)(Qb + 32);
        qf03 = *(const bf16x8*)(Qb + 48);
        const bf16* Qb2 = Qb + 32 * 64;
        qf10 = *(const bf16x8*)(Qb2 + 0);
        qf11 = *(const bf16x8*)(Qb2 + 16);
        qf12 = *(const bf16x8*)(Qb2 + 32);
        qf13 = *(const bf16x8*)(Qb2 + 48);
    }

    const bf16* Kh = Kg + (long)bh * 2048 * 64;
    const bf16* Vh = Vt + (long)bh * 64 * 2048;

    // O^T accumulators (col = q = l31): o<qb><ds>; m/l lane-local per qb
    f32x16 o00 = {}, o01 = {}, o10 = {}, o11 = {};
    float mv0 = -1e30f, mv1 = -1e30f, lv0 = 0.f, lv1 = 0.f;

    // async staging regs, named (frag-linear slots: slot = c*256 + t)
    int4 kr0, kr1, vr0, vr1;
    auto stage_load = [&](int kv0) {
        kr0 = *(const int4*)(Kh + (long)(kv0 + l31) * 64 + wave * 16 + hi * 8);
        kr1 = *(const int4*)(Kh + (long)(kv0 + 32 + l31) * 64 + wave * 16 + hi * 8);
        vr0 = *(const int4*)(Vh + (long)l31 * 2048 + kv0 + wave * 16 + hi * 8);
        vr1 = *(const int4*)(Vh + (long)(32 + l31) * 2048 + kv0 + wave * 16 + hi * 8);
    };
    auto stage_write = [&]() {
        *(int4*)(Ksh + t * 8) = kr0;
        *(int4*)(Ksh + (256 + t) * 8) = kr1;
        *(int4*)(Vsh + t * 8) = vr0;
        *(int4*)(Vsh + (256 + t) * 8) = vr1;
    };

    stage_load(0);
    stage_write();
    stage_load(64);
    __syncthreads();

    for (int kv0 = 0;; kv0 += 64) {
        // ---- q-block 0
        {
            f32x16 sA = {}, sB = {};
            __builtin_amdgcn_s_setprio(1);
            QKT(qf00, qf01, qf02, qf03, sA, sB);
            __builtin_amdgcn_s_setprio(0);
            SOFTMAX_PV(sA, sB, o00, o01, mv0, lv0);
        }
        // ---- q-block 1
        {
            f32x16 sA = {}, sB = {};
            __builtin_amdgcn_s_setprio(1);
            QKT(qf10, qf11, qf12, qf13, sA, sB);
            __builtin_amdgcn_s_setprio(0);
            SOFTMAX_PV(sA, sB, o10, o11, mv1, lv1);
        }

        if (kv0 == 2048 - 64) break;
        __syncthreads();
        stage_write();                       // tile kv0+64 from regs
        if (kv0 + 128 < 2048) stage_load(kv0 + 128);
        __syncthreads();
    }

    // ---- epilogue: O^T -> LDS transpose -> coalesced global stores
    long bb = bh >> 4, hh = bh & 15;
    EPI(o00, o01, lv0, 0);
    EPI(o10, o11, lv1, 32);
}

// ---------------------------------------------------------------- GEMM2: out = AO @ Wo^T + bo (fp32 out)
__global__ void gemm_out(const bf16* __restrict__ A, const bf16* __restrict__ B,
                         const float* __restrict__ bias, float* __restrict__ C) {
    const int K = 1024, N = 1024;
    __shared__ bf16 Alds[128 * 32];
    __shared__ bf16 Blds[128 * 32];
    int t = threadIdx.x;
    int lane = t & 63;
    int wave = t >> 6;
    int wm = wave >> 1, wn = wave & 1;
    int r = lane & 15, q = lane >> 4;
    long m0 = (long)blockIdx.y * 128;
    long n0 = (long)blockIdx.x * 128;
    const bf16* Ab = A + m0 * K;
    const bf16* Bb = B + n0 * K;

    f32x4 acc[4][4] = {};

    int srow = t >> 2;
    int scol = (t & 3) << 3;

    for (int k0 = 0; k0 < K; k0 += 32) {
        __syncthreads();
        gload_lds16(Ab + (long)srow * K + k0 + scol, Alds + t * 8);
        gload_lds16(Ab + (long)(srow + 64) * K + k0 + scol, Alds + 2048 + t * 8);
        gload_lds16(Bb + (long)srow * K + k0 + scol, Blds + t * 8);
        gload_lds16(Bb + (long)(srow + 64) * K + k0 + scol, Blds + 2048 + t * 8);
        __syncthreads();

        bf16x8 af[4], bfv[4];
#pragma unroll
        for (int mi = 0; mi < 4; mi++)
            af[mi] = *(const bf16x8*)(Alds + (wm * 64 + mi * 16 + r) * 32 + q * 8);
#pragma unroll
        for (int ni = 0; ni < 4; ni++)
            bfv[ni] = *(const bf16x8*)(Blds + (wn * 64 + ni * 16 + r) * 32 + q * 8);
#pragma unroll
        for (int mi = 0; mi < 4; mi++)
#pragma unroll
            for (int ni = 0; ni < 4; ni++)
                acc[mi][ni] = MFMA16(af[mi], bfv[ni], acc[mi][ni]);
    }

#pragma unroll
    for (int ni = 0; ni < 4; ni++) {
        int n = (int)n0 + wn * 64 + ni * 16 + r;
        float bn = bias[n];
#pragma unroll
        for (int mi = 0; mi < 4; mi++) {
#pragma unroll
            for (int rr = 0; rr < 4; rr++) {
                long m = m0 + wm * 64 + mi * 16 + q * 4 + rr;
                C[m * N + n] = acc[mi][ni][rr] + bn;
            }
        }
    }
}

// ---------------------------------------------------------------- launch
extern "C" void kernel_launch(void* const* d_in, const int* in_sizes, int n_in,
                              void* d_out, int out_size, void* d_ws, size_t ws_size,
                              hipStream_t stream) {
    const float* x    = (const float*)d_in[0];
    const float* Wqkv = (const float*)d_in[1];
    const float* bqkv = (const float*)d_in[2];
    const float* Wo   = (const float*)d_in[3];
    const float* bo   = (const float*)d_in[4];
    float* out = (float*)d_out;

    char* ws = (char*)d_ws;
    bf16* Xb  = (bf16*)(ws + 0);
    bf16* Wqb = (bf16*)(ws + 16777216);
    bf16* Wob = (bf16*)(ws + 23068672);
    bf16* Qb  = (bf16*)(ws + 25165824);
    bf16* Kb  = (bf16*)(ws + 41943040);
    bf16* Vtb = (bf16*)(ws + 58720256);
    bf16* AOb = (bf16*)(ws + 75497472);

    cvt_f32_bf16<<<8192, 256, 0, stream>>>(x, Xb, 8192 * 1024 / 4);
    cvt_f32_bf16<<<3072, 256, 0, stream>>>(Wqkv, Wqb, 3072 * 1024 / 4);
    cvt_f32_bf16<<<1024, 256, 0, stream>>>(Wo, Wob, 1024 * 1024 / 4);

    gemm_qkv<<<dim3(24, 64), 256, 0, stream>>>(Xb, Wqb, bqkv, Qb, Kb, Vtb);
    attn_fwd<<<512, 256, 0, stream>>>(Qb, Kb, Vtb, AOb);
    gemm_out<<<dim3(8, 64), 256, 0, stream>>>(AOb, Wob, bo, out);
}

// Round 7
// 218.180 us; speedup vs baseline: 1.3561x; 1.1548x over previous
//
#include <hip/hip_runtime.h>
#include <hip/hip_bf16.h>

using bf16 = __hip_bfloat16;
typedef __attribute__((ext_vector_type(8))) __bf16 bf16x8;
typedef __attribute__((ext_vector_type(4))) float f32x4;
typedef __attribute__((ext_vector_type(16))) float f32x16;
typedef __attribute__((ext_vector_type(4))) unsigned u32x4;

#define MFMA16(a, b, c) __builtin_amdgcn_mfma_f32_16x16x32_bf16((a), (b), (c), 0, 0, 0)
#define MFMA32(a, b, c) __builtin_amdgcn_mfma_f32_32x32x16_bf16((a), (b), (c), 0, 0, 0)

static __device__ __forceinline__ void gload_lds16(const bf16* g, bf16* l) {
    __builtin_amdgcn_global_load_lds(
        (__attribute__((address_space(1))) void*)(bf16*)(g),
        (__attribute__((address_space(3))) void*)(l), 16, 0, 0);
}

static __device__ __forceinline__ unsigned cvtpk(float lo, float hi) {
    unsigned r;
    asm("v_cvt_pk_bf16_f32 %0, %1, %2" : "=v"(r) : "v"(lo), "v"(hi));
    return r;
}

// ---------------------------------------------------------------- convert
__global__ void cvt_f32_bf16(const float* __restrict__ in, bf16* __restrict__ out, int n4) {
    int i = blockIdx.x * 256 + threadIdx.x;
    if (i >= n4) return;
    float4 v = ((const float4*)in)[i];
    bf16 t[4];
    t[0] = __float2bfloat16(v.x);
    t[1] = __float2bfloat16(v.y);
    t[2] = __float2bfloat16(v.z);
    t[3] = __float2bfloat16(v.w);
    *(uint2*)(out + 4l * i) = *(uint2*)t;
}

// ---------------------------------------------------------------- GEMM1: qkv = x @ Wqkv^T + b, scatter to Q,K,V^T (bf16)
__global__ void gemm_qkv(const bf16* __restrict__ A, const bf16* __restrict__ B,
                         const float* __restrict__ bias,
                         bf16* __restrict__ Qo, bf16* __restrict__ Ko, bf16* __restrict__ Vt) {
    const int K = 1024;
    __shared__ bf16 Alds[128 * 32];
    __shared__ bf16 Blds[128 * 32];
    int t = threadIdx.x;
    int lane = t & 63;
    int wave = t >> 6;
    int wm = wave >> 1, wn = wave & 1;
    int r = lane & 15, q = lane >> 4;
    long m0 = (long)blockIdx.y * 128;
    long n0 = (long)blockIdx.x * 128;
    const bf16* Ab = A + m0 * K;
    const bf16* Bb = B + n0 * K;

    f32x4 acc[4][4] = {};

    int srow = t >> 2;
    int scol = (t & 3) << 3;

    for (int k0 = 0; k0 < K; k0 += 32) {
        __syncthreads();
        gload_lds16(Ab + (long)srow * K + k0 + scol, Alds + t * 8);
        gload_lds16(Ab + (long)(srow + 64) * K + k0 + scol, Alds + 2048 + t * 8);
        gload_lds16(Bb + (long)srow * K + k0 + scol, Blds + t * 8);
        gload_lds16(Bb + (long)(srow + 64) * K + k0 + scol, Blds + 2048 + t * 8);
        __syncthreads();

        bf16x8 af[4], bfv[4];
#pragma unroll
        for (int mi = 0; mi < 4; mi++)
            af[mi] = *(const bf16x8*)(Alds + (wm * 64 + mi * 16 + r) * 32 + q * 8);
#pragma unroll
        for (int ni = 0; ni < 4; ni++)
            bfv[ni] = *(const bf16x8*)(Blds + (wn * 64 + ni * 16 + r) * 32 + q * 8);
#pragma unroll
        for (int mi = 0; mi < 4; mi++)
#pragma unroll
            for (int ni = 0; ni < 4; ni++)
                acc[mi][ni] = MFMA16(af[mi], bfv[ni], acc[mi][ni]);
    }

#pragma unroll
    for (int ni = 0; ni < 4; ni++) {
        int n = (int)n0 + wn * 64 + ni * 16 + r;
        float bn = bias[n];
        int h = n / 192;
        int rem = n % 192;
        int part = rem >> 6;
        int d = rem & 63;
#pragma unroll
        for (int mi = 0; mi < 4; mi++) {
#pragma unroll
            for (int rr = 0; rr < 4; rr++) {
                int m = (int)m0 + wm * 64 + mi * 16 + q * 4 + rr;
                int b = m >> 11;
                int row = m & 2047;
                long bh = b * 16 + h;
                bf16 bv = __float2bfloat16(acc[mi][ni][rr] + bn);
                if (part == 0)      Qo[(bh * 2048 + row) * 64 + d] = bv;
                else if (part == 1) Ko[(bh * 2048 + row) * 64 + d] = bv;
                else                Vt[(bh * 64 + d) * 2048 + row] = bv;
            }
        }
    }
}

// ---------------------------------------------------------------- attention
// 32x32 MFMA, swapped QK^T (S^T), in-register P, O^T accumulation, defer-max.
// Block: 4 waves x 64 q; KVBLK=128 (2 frag-linear half-banks, one barrier pair
// per 128 kv); 512 blocks XCD-swizzled. permlane32_swap for the P exchange.

#define PACK8(S, OFF, OUTV) { \
    unsigned A0 = cvtpk(S[OFF+0], S[OFF+1]); \
    unsigned B0 = cvtpk(S[OFF+4], S[OFF+5]); \
    unsigned A1 = cvtpk(S[OFF+2], S[OFF+3]); \
    unsigned B1 = cvtpk(S[OFF+6], S[OFF+7]); \
    asm("v_permlane32_swap_b32 %0, %1" : "+v"(A0), "+v"(B0)); \
    asm("v_permlane32_swap_b32 %0, %1" : "+v"(A1), "+v"(B1)); \
    u32x4 W; W.x = A0; W.y = A1; W.z = B0; W.w = B1; \
    OUTV = __builtin_bit_cast(bf16x8, W); }

#define QKT(KB, QF0, QF1, QF2, QF3, SA, SB) { \
    bf16x8 kA, kB; \
    kA = *(const bf16x8*)(KB + (0 * 64 + lane) * 8); \
    kB = *(const bf16x8*)(KB + (256 + 0 * 64 + lane) * 8); \
    SA = MFMA32(kA, QF0, SA);  SB = MFMA32(kB, QF0, SB); \
    kA = *(const bf16x8*)(KB + (1 * 64 + lane) * 8); \
    kB = *(const bf16x8*)(KB + (256 + 1 * 64 + lane) * 8); \
    SA = MFMA32(kA, QF1, SA);  SB = MFMA32(kB, QF1, SB); \
    kA = *(const bf16x8*)(KB + (2 * 64 + lane) * 8); \
    kB = *(const bf16x8*)(KB + (256 + 2 * 64 + lane) * 8); \
    SA = MFMA32(kA, QF2, SA);  SB = MFMA32(kB, QF2, SB); \
    kA = *(const bf16x8*)(KB + (3 * 64 + lane) * 8); \
    kB = *(const bf16x8*)(KB + (256 + 3 * 64 + lane) * 8); \
    SA = MFMA32(kA, QF3, SA);  SB = MFMA32(kB, QF3, SB); }

#define PVSTEP(VB, KF, PF, O0, O1) { \
    bf16x8 vA = *(const bf16x8*)(VB + (KF * 64 + lane) * 8); \
    bf16x8 vB = *(const bf16x8*)(VB + (256 + KF * 64 + lane) * 8); \
    O0 = MFMA32(vA, PF, O0); \
    O1 = MFMA32(vB, PF, O1); }

#define SOFTMAX_PV(VB, SA, SB, O0, O1, MV, LV) do { \
    float x0 = fmaxf(fmaxf(SA[0], SA[1]), fmaxf(SA[2], SA[3])); \
    float x1 = fmaxf(fmaxf(SA[4], SA[5]), fmaxf(SA[6], SA[7])); \
    float x2 = fmaxf(fmaxf(SA[8], SA[9]), fmaxf(SA[10], SA[11])); \
    float x3 = fmaxf(fmaxf(SA[12], SA[13]), fmaxf(SA[14], SA[15])); \
    float y0 = fmaxf(fmaxf(SB[0], SB[1]), fmaxf(SB[2], SB[3])); \
    float y1 = fmaxf(fmaxf(SB[4], SB[5]), fmaxf(SB[6], SB[7])); \
    float y2 = fmaxf(fmaxf(SB[8], SB[9]), fmaxf(SB[10], SB[11])); \
    float y3 = fmaxf(fmaxf(SB[12], SB[13]), fmaxf(SB[14], SB[15])); \
    float pm = fmaxf(fmaxf(fmaxf(x0, x1), fmaxf(x2, x3)), \
                     fmaxf(fmaxf(y0, y1), fmaxf(y2, y3))); \
    pm = fmaxf(pm, __shfl_xor(pm, 32)); \
    bool resc = !__all(pm <= MV + 8.0f); \
    float al = 1.f; \
    if (resc) { float mn = fmaxf(MV, pm); al = __builtin_amdgcn_exp2f((MV - mn) * C1); MV = mn; } \
    float mc = MV * C1; \
    float ts = 0.f; \
    _Pragma("unroll") for (int e = 0; e < 16; ++e) { float p = __builtin_amdgcn_exp2f(SA[e] * C1 - mc); SA[e] = p; ts += p; } \
    _Pragma("unroll") for (int e = 0; e < 16; ++e) { float p = __builtin_amdgcn_exp2f(SB[e] * C1 - mc); SB[e] = p; ts += p; } \
    ts += __shfl_xor(ts, 32); \
    if (resc) { \
        LV = LV * al + ts; \
        _Pragma("unroll") for (int e = 0; e < 16; ++e) { O0[e] *= al; O1[e] *= al; } \
    } else { LV += ts; } \
    bf16x8 pf0, pf1, pf2, pf3; \
    PACK8(SA, 0, pf0); PACK8(SA, 8, pf1); PACK8(SB, 0, pf2); PACK8(SB, 8, pf3); \
    __builtin_amdgcn_s_setprio(1); \
    PVSTEP(VB, 0, pf0, O0, O1); \
    PVSTEP(VB, 1, pf1, O0, O1); \
    PVSTEP(VB, 2, pf2, O0, O1); \
    PVSTEP(VB, 3, pf3, O0, O1); \
    __builtin_amdgcn_s_setprio(0); \
} while (0)

#define PROC_HALF(KB, VB) do { \
    { \
        f32x16 sA = {}, sB = {}; \
        __builtin_amdgcn_s_setprio(1); \
        QKT(KB, qf00, qf01, qf02, qf03, sA, sB); \
        __builtin_amdgcn_s_setprio(0); \
        SOFTMAX_PV(VB, sA, sB, o00, o01, mv0, lv0); \
    } \
    { \
        f32x16 sA = {}, sB = {}; \
        __builtin_amdgcn_s_setprio(1); \
        QKT(KB, qf10, qf11, qf12, qf13, sA, sB); \
        __builtin_amdgcn_s_setprio(0); \
        SOFTMAX_PV(VB, sA, sB, o10, o11, mv1, lv1); \
    } \
} while (0)

#define EPI(O0v, O1v, LVv, QBOFF) { \
    __syncthreads(); \
    float il = 1.f / LVv; \
    char* wbase = (char*)smem + wave * 4096 + l31 * 128; \
    _Pragma("unroll") for (int j = 0; j < 4; ++j) { \
        unsigned wlo = cvtpk(O0v[4 * j] * il, O0v[4 * j + 1] * il); \
        unsigned whi = cvtpk(O0v[4 * j + 2] * il, O0v[4 * j + 3] * il); \
        int b8 = 2 * j + hi; int b8s = b8 ^ ((l31 & 7) << 1); \
        uint2 val; val.x = wlo; val.y = whi; \
        *(uint2*)(wbase + b8s * 8) = val; } \
    _Pragma("unroll") for (int j = 0; j < 4; ++j) { \
        unsigned wlo = cvtpk(O1v[4 * j] * il, O1v[4 * j + 1] * il); \
        unsigned whi = cvtpk(O1v[4 * j + 2] * il, O1v[4 * j + 3] * il); \
        int b8 = 8 + 2 * j + hi; int b8s = b8 ^ ((l31 & 7) << 1); \
        uint2 val; val.x = wlo; val.y = whi; \
        *(uint2*)(wbase + b8s * 8) = val; } \
    __syncthreads(); \
    { int rid = t >> 1, hf = t & 1; \
      int wv = rid >> 5, qq = rid & 31; \
      long orow = (long)qt * 256 + wv * 64 + (QBOFF) + qq; \
      const char* rbase = (const char*)smem + wv * 4096 + qq * 128; \
      bf16* dst = AO + (bb * 2048 + orow) * 1024 + hh * 64 + hf * 32; \
      _Pragma("unroll") for (int k = 0; k < 4; ++k) { \
          int b8 = hf * 8 + 2 * k; int b8s = b8 ^ ((qq & 7) << 1); \
          int4 v = *(const int4*)(rbase + b8s * 8); \
          *(int4*)(dst + k * 8) = v; } } }

__global__ __launch_bounds__(256, 2) void attn_fwd(const bf16* __restrict__ Q,
                                                   const bf16* __restrict__ Kg,
                                                   const bf16* __restrict__ Vt,
                                                   bf16* __restrict__ AO) {
    __shared__ bf16 smem[16384];   // K halves [0..8191], V halves [8192..16383]
    bf16* Ksh0 = smem;
    bf16* Ksh1 = smem + 4096;
    bf16* Vsh0 = smem + 8192;
    bf16* Vsh1 = smem + 12288;
    const int t = threadIdx.x;
    const int lane = t & 63, wave = t >> 6;
    const int l31 = lane & 31, hi = lane >> 5;
    // XCD swizzle: 512 blocks; xcd = bid&7 owns bh in [xcd*8, xcd*8+8)
    const int bid = blockIdx.x;
    const int xcd = bid & 7, idx = bid >> 3;
    const int bh = xcd * 8 + (idx >> 3);
    const int qt = idx & 7;
    const float C1 = 0.18033688011112042f;   // log2(e)/sqrt(64)

    // Q fragments in registers all kernel (2 q-blocks x 4 k-chunks), all named
    bf16x8 qf00, qf01, qf02, qf03, qf10, qf11, qf12, qf13;
    {
        const bf16* Qb = Q + ((long)bh * 2048 + qt * 256 + wave * 64 + l31) * 64 + hi * 8;
        qf00 = *(const bf16x8*)(Qb + 0);
        qf01 = *(const bf16x8*)(Qb + 16);
        qf02 = *(const bf16x8*)(Qb + 32);
        qf03 = *(const bf16x8*)(Qb + 48);
        const bf16* Qb2 = Qb + 32 * 64;
        qf10 = *(const bf16x8*)(Qb2 + 0);
        qf11 = *(const bf16x8*)(Qb2 + 16);
        qf12 = *(const bf16x8*)(Qb2 + 32);
        qf13 = *(const bf16x8*)(Qb2 + 48);
    }

    const bf16* Kh = Kg + (long)bh * 2048 * 64;
    const bf16* Vh = Vt + (long)bh * 64 * 2048;

    // O^T accumulators (col = q = l31): o<qb><ds>; m/l lane-local per qb
    f32x16 o00 = {}, o01 = {}, o10 = {}, o11 = {};
    float mv0 = -1e30f, mv1 = -1e30f, lv0 = 0.f, lv1 = 0.f;

    // async staging regs, named (frag-linear slots)
    int4 kr0, kr1, kr2, kr3, vr0, vr1, vr2, vr3;
    const int off = wave * 16 + hi * 8;
    auto stage_load = [&](int kv0) {
        kr0 = *(const int4*)(Kh + (long)(kv0 + l31) * 64 + off);
        kr1 = *(const int4*)(Kh + (long)(kv0 + 32 + l31) * 64 + off);
        kr2 = *(const int4*)(Kh + (long)(kv0 + 64 + l31) * 64 + off);
        kr3 = *(const int4*)(Kh + (long)(kv0 + 96 + l31) * 64 + off);
        vr0 = *(const int4*)(Vh + (long)l31 * 2048 + kv0 + off);
        vr1 = *(const int4*)(Vh + (long)(32 + l31) * 2048 + kv0 + off);
        vr2 = *(const int4*)(Vh + (long)l31 * 2048 + kv0 + 64 + off);
        vr3 = *(const int4*)(Vh + (long)(32 + l31) * 2048 + kv0 + 64 + off);
    };
    auto stage_write = [&]() {
        *(int4*)(Ksh0 + t * 8) = kr0;
        *(int4*)(Ksh0 + (256 + t) * 8) = kr1;
        *(int4*)(Ksh1 + t * 8) = kr2;
        *(int4*)(Ksh1 + (256 + t) * 8) = kr3;
        *(int4*)(Vsh0 + t * 8) = vr0;
        *(int4*)(Vsh0 + (256 + t) * 8) = vr1;
        *(int4*)(Vsh1 + t * 8) = vr2;
        *(int4*)(Vsh1 + (256 + t) * 8) = vr3;
    };

    stage_load(0);
    stage_write();
    stage_load(128);
    __syncthreads();

    for (int kv0 = 0;; kv0 += 128) {
        PROC_HALF(Ksh0, Vsh0);   // kv [kv0, kv0+64)
        PROC_HALF(Ksh1, Vsh1);   // kv [kv0+64, kv0+128)

        if (kv0 == 2048 - 128) break;
        __syncthreads();
        stage_write();                       // tile kv0+128 from regs
        if (kv0 + 256 < 2048) stage_load(kv0 + 256);
        __syncthreads();
    }

    // ---- epilogue: O^T -> LDS transpose -> coalesced global stores
    long bb = bh >> 4, hh = bh & 15;
    EPI(o00, o01, lv0, 0);
    EPI(o10, o11, lv1, 32);
}

// ---------------------------------------------------------------- GEMM2: out = AO @ Wo^T + bo (fp32 out)
__global__ void gemm_out(const bf16* __restrict__ A, const bf16* __restrict__ B,
                         const float* __restrict__ bias, float* __restrict__ C) {
    const int K = 1024, N = 1024;
    __shared__ bf16 Alds[128 * 32];
    __shared__ bf16 Blds[128 * 32];
    int t = threadIdx.x;
    int lane = t & 63;
    int wave = t >> 6;
    int wm = wave >> 1, wn = wave & 1;
    int r = lane & 15, q = lane >> 4;
    long m0 = (long)blockIdx.y * 128;
    long n0 = (long)blockIdx.x * 128;
    const bf16* Ab = A + m0 * K;
    const bf16* Bb = B + n0 * K;

    f32x4 acc[4][4] = {};

    int srow = t >> 2;
    int scol = (t & 3) << 3;

    for (int k0 = 0; k0 < K; k0 += 32) {
        __syncthreads();
        gload_lds16(Ab + (long)srow * K + k0 + scol, Alds + t * 8);
        gload_lds16(Ab + (long)(srow + 64) * K + k0 + scol, Alds + 2048 + t * 8);
        gload_lds16(Bb + (long)srow * K + k0 + scol, Blds + t * 8);
        gload_lds16(Bb + (long)(srow + 64) * K + k0 + scol, Blds + 2048 + t * 8);
        __syncthreads();

        bf16x8 af[4], bfv[4];
#pragma unroll
        for (int mi = 0; mi < 4; mi++)
            af[mi] = *(const bf16x8*)(Alds + (wm * 64 + mi * 16 + r) * 32 + q * 8);
#pragma unroll
        for (int ni = 0; ni < 4; ni++)
            bfv[ni] = *(const bf16x8*)(Blds + (wn * 64 + ni * 16 + r) * 32 + q * 8);
#pragma unroll
        for (int mi = 0; mi < 4; mi++)
#pragma unroll
            for (int ni = 0; ni < 4; ni++)
                acc[mi][ni] = MFMA16(af[mi], bfv[ni], acc[mi][ni]);
    }

#pragma unroll
    for (int ni = 0; ni < 4; ni++) {
        int n = (int)n0 + wn * 64 + ni * 16 + r;
        float bn = bias[n];
#pragma unroll
        for (int mi = 0; mi < 4; mi++) {
#pragma unroll
            for (int rr = 0; rr < 4; rr++) {
                long m = m0 + wm * 64 + mi * 16 + q * 4 + rr;
                C[m * N + n] = acc[mi][ni][rr] + bn;
            }
        }
    }
}

// ---------------------------------------------------------------- launch
extern "C" void kernel_launch(void* const* d_in, const int* in_sizes, int n_in,
                              void* d_out, int out_size, void* d_ws, size_t ws_size,
                              hipStream_t stream) {
    const float* x    = (const float*)d_in[0];
    const float* Wqkv = (const float*)d_in[1];
    const float* bqkv = (const float*)d_in[2];
    const float* Wo   = (const float*)d_in[3];
    const float* bo   = (const float*)d_in[4];
    float* out = (float*)d_out;

    char* ws = (char*)d_ws;
    bf16* Xb  = (bf16*)(ws + 0);
    bf16* Wqb = (bf16*)(ws + 16777216);
    bf16* Wob = (bf16*)(ws + 23068672);
    bf16* Qb  = (bf16*)(ws + 25165824);
    bf16* Kb  = (bf16*)(ws + 41943040);
    bf16* Vtb = (bf16*)(ws + 58720256);
    bf16* AOb = (bf16*)(ws + 75497472);

    cvt_f32_bf16<<<8192, 256, 0, stream>>>(x, Xb, 8192 * 1024 / 4);
    cvt_f32_bf16<<<3072, 256, 0, stream>>>(Wqkv, Wqb, 3072 * 1024 / 4);
    cvt_f32_bf16<<<1024, 256, 0, stream>>>(Wo, Wob, 1024 * 1024 / 4);

    gemm_qkv<<<dim3(24, 64), 256, 0, stream>>>(Xb, Wqb, bqkv, Qb, Kb, Vtb);
    attn_fwd<<<512, 256, 0, stream>>>(Qb, Kb, Vtb, AOb);
    gemm_out<<<dim3(8, 64), 256, 0, stream>>>(AOb, Wob, bo, out);
}

// Round 8
// 205.492 us; speedup vs baseline: 1.4399x; 1.0617x over previous
//
#include <hip/hip_runtime.h>
#include <hip/hip_bf16.h>

using bf16 = __hip_bfloat16;
typedef __attribute__((ext_vector_type(8))) __bf16 bf16x8;
typedef __attribute__((ext_vector_type(4))) float f32x4;
typedef __attribute__((ext_vector_type(16))) float f32x16;
typedef __attribute__((ext_vector_type(4))) unsigned u32x4;

#define MFMA16(a, b, c) __builtin_amdgcn_mfma_f32_16x16x32_bf16((a), (b), (c), 0, 0, 0)
#define MFMA32(a, b, c) __builtin_amdgcn_mfma_f32_32x32x16_bf16((a), (b), (c), 0, 0, 0)

static __device__ __forceinline__ void gload_lds16(const bf16* g, bf16* l) {
    __builtin_amdgcn_global_load_lds(
        (__attribute__((address_space(1))) void*)(bf16*)(g),
        (__attribute__((address_space(3))) void*)(l), 16, 0, 0);
}

static __device__ __forceinline__ unsigned cvtpk(float lo, float hi) {
    unsigned r;
    asm("v_cvt_pk_bf16_f32 %0, %1, %2" : "=v"(r) : "v"(lo), "v"(hi));
    return r;
}

// ---------------------------------------------------------------- convert
__global__ void cvt_f32_bf16(const float* __restrict__ in, bf16* __restrict__ out, int n4) {
    int i = blockIdx.x * 256 + threadIdx.x;
    if (i >= n4) return;
    float4 v = ((const float4*)in)[i];
    bf16 t[4];
    t[0] = __float2bfloat16(v.x);
    t[1] = __float2bfloat16(v.y);
    t[2] = __float2bfloat16(v.z);
    t[3] = __float2bfloat16(v.w);
    *(uint2*)(out + 4l * i) = *(uint2*)t;
}

// ---------------------------------------------------------------- GEMM1: qkv = x @ Wqkv^T + b, scatter to Q,K,V^T (bf16)
__global__ void gemm_qkv(const bf16* __restrict__ A, const bf16* __restrict__ B,
                         const float* __restrict__ bias,
                         bf16* __restrict__ Qo, bf16* __restrict__ Ko, bf16* __restrict__ Vt) {
    const int K = 1024;
    __shared__ bf16 Alds[128 * 32];
    __shared__ bf16 Blds[128 * 32];
    int t = threadIdx.x;
    int lane = t & 63;
    int wave = t >> 6;
    int wm = wave >> 1, wn = wave & 1;
    int r = lane & 15, q = lane >> 4;
    long m0 = (long)blockIdx.y * 128;
    long n0 = (long)blockIdx.x * 128;
    const bf16* Ab = A + m0 * K;
    const bf16* Bb = B + n0 * K;

    f32x4 acc[4][4] = {};

    int srow = t >> 2;
    int scol = (t & 3) << 3;

    for (int k0 = 0; k0 < K; k0 += 32) {
        __syncthreads();
        gload_lds16(Ab + (long)srow * K + k0 + scol, Alds + t * 8);
        gload_lds16(Ab + (long)(srow + 64) * K + k0 + scol, Alds + 2048 + t * 8);
        gload_lds16(Bb + (long)srow * K + k0 + scol, Blds + t * 8);
        gload_lds16(Bb + (long)(srow + 64) * K + k0 + scol, Blds + 2048 + t * 8);
        __syncthreads();

        bf16x8 af[4], bfv[4];
#pragma unroll
        for (int mi = 0; mi < 4; mi++)
            af[mi] = *(const bf16x8*)(Alds + (wm * 64 + mi * 16 + r) * 32 + q * 8);
#pragma unroll
        for (int ni = 0; ni < 4; ni++)
            bfv[ni] = *(const bf16x8*)(Blds + (wn * 64 + ni * 16 + r) * 32 + q * 8);
#pragma unroll
        for (int mi = 0; mi < 4; mi++)
#pragma unroll
            for (int ni = 0; ni < 4; ni++)
                acc[mi][ni] = MFMA16(af[mi], bfv[ni], acc[mi][ni]);
    }

#pragma unroll
    for (int ni = 0; ni < 4; ni++) {
        int n = (int)n0 + wn * 64 + ni * 16 + r;
        float bn = bias[n];
        int h = n / 192;
        int rem = n % 192;
        int part = rem >> 6;
        int d = rem & 63;
#pragma unroll
        for (int mi = 0; mi < 4; mi++) {
#pragma unroll
            for (int rr = 0; rr < 4; rr++) {
                int m = (int)m0 + wm * 64 + mi * 16 + q * 4 + rr;
                int b = m >> 11;
                int row = m & 2047;
                long bh = b * 16 + h;
                bf16 bv = __float2bfloat16(acc[mi][ni][rr] + bn);
                if (part == 0)      Qo[(bh * 2048 + row) * 64 + d] = bv;
                else if (part == 1) Ko[(bh * 2048 + row) * 64 + d] = bv;
                else                Vt[(bh * 64 + d) * 2048 + row] = bv;
            }
        }
    }
}

// ---------------------------------------------------------------- attention
// 8 waves x 32 q = 256 q/block; KVBLK=64 double-buffered via global_load_lds
// (frag-linear LDS is exactly wave-uniform-base + lane*16 -> DMA-compatible).
// Swapped QK^T, in-register P (permlane32_swap), O^T accum, defer-max.

#define PACK8(S, OFF, OUTV) { \
    unsigned A0 = cvtpk(S[OFF+0], S[OFF+1]); \
    unsigned B0 = cvtpk(S[OFF+4], S[OFF+5]); \
    unsigned A1 = cvtpk(S[OFF+2], S[OFF+3]); \
    unsigned B1 = cvtpk(S[OFF+6], S[OFF+7]); \
    asm("v_permlane32_swap_b32 %0, %1" : "+v"(A0), "+v"(B0)); \
    asm("v_permlane32_swap_b32 %0, %1" : "+v"(A1), "+v"(B1)); \
    u32x4 W; W.x = A0; W.y = A1; W.z = B0; W.w = B1; \
    OUTV = __builtin_bit_cast(bf16x8, W); }

#define COMPUTE(KB, VB) do { \
    f32x16 sA = {}, sB = {}; \
    __builtin_amdgcn_s_setprio(1); \
    { \
        bf16x8 kA, kB; \
        kA = *(const bf16x8*)(KB + (0 * 64 + lane) * 8); \
        kB = *(const bf16x8*)(KB + (256 + 0 * 64 + lane) * 8); \
        sA = MFMA32(kA, qf0, sA);  sB = MFMA32(kB, qf0, sB); \
        kA = *(const bf16x8*)(KB + (1 * 64 + lane) * 8); \
        kB = *(const bf16x8*)(KB + (256 + 1 * 64 + lane) * 8); \
        sA = MFMA32(kA, qf1, sA);  sB = MFMA32(kB, qf1, sB); \
        kA = *(const bf16x8*)(KB + (2 * 64 + lane) * 8); \
        kB = *(const bf16x8*)(KB + (256 + 2 * 64 + lane) * 8); \
        sA = MFMA32(kA, qf2, sA);  sB = MFMA32(kB, qf2, sB); \
        kA = *(const bf16x8*)(KB + (3 * 64 + lane) * 8); \
        kB = *(const bf16x8*)(KB + (256 + 3 * 64 + lane) * 8); \
        sA = MFMA32(kA, qf3, sA);  sB = MFMA32(kB, qf3, sB); \
    } \
    __builtin_amdgcn_s_setprio(0); \
    float x0 = fmaxf(fmaxf(sA[0], sA[1]), fmaxf(sA[2], sA[3])); \
    float x1 = fmaxf(fmaxf(sA[4], sA[5]), fmaxf(sA[6], sA[7])); \
    float x2 = fmaxf(fmaxf(sA[8], sA[9]), fmaxf(sA[10], sA[11])); \
    float x3 = fmaxf(fmaxf(sA[12], sA[13]), fmaxf(sA[14], sA[15])); \
    float y0 = fmaxf(fmaxf(sB[0], sB[1]), fmaxf(sB[2], sB[3])); \
    float y1 = fmaxf(fmaxf(sB[4], sB[5]), fmaxf(sB[6], sB[7])); \
    float y2 = fmaxf(fmaxf(sB[8], sB[9]), fmaxf(sB[10], sB[11])); \
    float y3 = fmaxf(fmaxf(sB[12], sB[13]), fmaxf(sB[14], sB[15])); \
    float pm = fmaxf(fmaxf(fmaxf(x0, x1), fmaxf(x2, x3)), \
                     fmaxf(fmaxf(y0, y1), fmaxf(y2, y3))); \
    pm = fmaxf(pm, __shfl_xor(pm, 32)); \
    bool resc = !__all(pm <= mv + 8.0f); \
    if (resc) { \
        float mn = fmaxf(mv, pm); \
        float al = __builtin_amdgcn_exp2f((mv - mn) * C1); \
        mv = mn; \
        lv *= al; \
        _Pragma("unroll") for (int e = 0; e < 16; ++e) { o0[e] *= al; o1[e] *= al; } \
    } \
    float mc = mv * C1; \
    float ts = 0.f; \
    _Pragma("unroll") for (int e = 0; e < 16; ++e) { float p = __builtin_amdgcn_exp2f(sA[e] * C1 - mc); sA[e] = p; ts += p; } \
    _Pragma("unroll") for (int e = 0; e < 16; ++e) { float p = __builtin_amdgcn_exp2f(sB[e] * C1 - mc); sB[e] = p; ts += p; } \
    ts += __shfl_xor(ts, 32); \
    lv += ts; \
    bf16x8 pf0, pf1, pf2, pf3; \
    PACK8(sA, 0, pf0); PACK8(sA, 8, pf1); PACK8(sB, 0, pf2); PACK8(sB, 8, pf3); \
    __builtin_amdgcn_s_setprio(1); \
    { \
        bf16x8 vA, vB; \
        vA = *(const bf16x8*)(VB + (0 * 64 + lane) * 8); \
        vB = *(const bf16x8*)(VB + (256 + 0 * 64 + lane) * 8); \
        o0 = MFMA32(vA, pf0, o0);  o1 = MFMA32(vB, pf0, o1); \
        vA = *(const bf16x8*)(VB + (1 * 64 + lane) * 8); \
        vB = *(const bf16x8*)(VB + (256 + 1 * 64 + lane) * 8); \
        o0 = MFMA32(vA, pf1, o0);  o1 = MFMA32(vB, pf1, o1); \
        vA = *(const bf16x8*)(VB + (2 * 64 + lane) * 8); \
        vB = *(const bf16x8*)(VB + (256 + 2 * 64 + lane) * 8); \
        o0 = MFMA32(vA, pf2, o0);  o1 = MFMA32(vB, pf2, o1); \
        vA = *(const bf16x8*)(VB + (3 * 64 + lane) * 8); \
        vB = *(const bf16x8*)(VB + (256 + 3 * 64 + lane) * 8); \
        o0 = MFMA32(vA, pf3, o0);  o1 = MFMA32(vB, pf3, o1); \
    } \
    __builtin_amdgcn_s_setprio(0); \
} while (0)

__global__ __launch_bounds__(512, 4) void attn_fwd(const bf16* __restrict__ Q,
                                                   const bf16* __restrict__ Kg,
                                                   const bf16* __restrict__ Vt,
                                                   bf16* __restrict__ AO) {
    __shared__ bf16 smem[16384];   // [K0 4096][V0 4096][K1 4096][V1 4096]
    bf16* K0 = smem;
    bf16* V0 = smem + 4096;
    bf16* K1 = smem + 8192;
    bf16* V1 = smem + 12288;
    const int t = threadIdx.x;
    const int lane = t & 63, wave = t >> 6;
    const int l31 = lane & 31, hi = lane >> 5;
    // XCD swizzle: 512 blocks; xcd = bid&7 owns bh in [xcd*8, xcd*8+8)
    const int bid = blockIdx.x;
    const int xcd = bid & 7, idx = bid >> 3;
    const int bh = xcd * 8 + (idx >> 3);
    const int qt = idx & 7;
    const float C1 = 0.18033688011112042f;   // log2(e)/sqrt(64)

    // Q fragments (one 32-q block per wave)
    bf16x8 qf0, qf1, qf2, qf3;
    {
        const bf16* Qb = Q + ((long)bh * 2048 + qt * 256 + wave * 32 + l31) * 64 + hi * 8;
        qf0 = *(const bf16x8*)(Qb + 0);
        qf1 = *(const bf16x8*)(Qb + 16);
        qf2 = *(const bf16x8*)(Qb + 32);
        qf3 = *(const bf16x8*)(Qb + 48);
    }

    const bf16* Kh = Kg + (long)bh * 2048 * 64;
    const bf16* Vh = Vt + (long)bh * 64 * 2048;

    // staging geometry: thread t -> LDS slot t (frag-linear), source (r, c)
    const int sr = ((t >> 8) << 5) + (t & 31);          // 0..63
    const int sc = ((t >> 6) & 3) * 16 + ((t >> 5) & 1) * 8;

    f32x16 o0 = {}, o1 = {};
    float mv = -1e30f, lv = 0.f;

    auto issue_stage = [&](bf16* Kb, bf16* Vb, int kv0) {
        gload_lds16(Kh + (long)(kv0 + sr) * 64 + sc, Kb + t * 8);
        gload_lds16(Vh + (long)sr * 2048 + kv0 + sc, Vb + t * 8);
    };

    issue_stage(K0, V0, 0);
    __syncthreads();                         // K0/V0 ready

    for (int kv0 = 0;; kv0 += 128) {
        issue_stage(K1, V1, kv0 + 64);       // prefetch tile B
        COMPUTE(K0, V0);                     // tile A
        __syncthreads();                     // K1 ready, K0 free
        if (kv0 + 128 < 2048) issue_stage(K0, V0, kv0 + 128);
        COMPUTE(K1, V1);                     // tile B
        if (kv0 + 128 >= 2048) break;
        __syncthreads();                     // K0' ready, K1 free
    }

    // ---- epilogue: O^T -> LDS transpose -> coalesced global stores
    long bb = bh >> 4, hh = bh & 15;
    __syncthreads();
    float il = 1.f / lv;
    char* wbase = (char*)smem + wave * 4096 + l31 * 128;
#pragma unroll
    for (int j = 0; j < 4; ++j) {
        unsigned wlo = cvtpk(o0[4 * j] * il, o0[4 * j + 1] * il);
        unsigned whi = cvtpk(o0[4 * j + 2] * il, o0[4 * j + 3] * il);
        int b8 = 2 * j + hi;
        int b8s = b8 ^ ((l31 & 7) << 1);
        uint2 val; val.x = wlo; val.y = whi;
        *(uint2*)(wbase + b8s * 8) = val;
    }
#pragma unroll
    for (int j = 0; j < 4; ++j) {
        unsigned wlo = cvtpk(o1[4 * j] * il, o1[4 * j + 1] * il);
        unsigned whi = cvtpk(o1[4 * j + 2] * il, o1[4 * j + 3] * il);
        int b8 = 8 + 2 * j + hi;
        int b8s = b8 ^ ((l31 & 7) << 1);
        uint2 val; val.x = wlo; val.y = whi;
        *(uint2*)(wbase + b8s * 8) = val;
    }
    __syncthreads();
    {
        int rid = t >> 1, hf = t & 1;
        int wv = rid >> 5, qq = rid & 31;
        long orow = (long)qt * 256 + wv * 32 + qq;
        const char* rbase = (const char*)smem + wv * 4096 + qq * 128;
        bf16* dst = AO + (bb * 2048 + orow) * 1024 + hh * 64 + hf * 32;
#pragma unroll
        for (int k = 0; k < 4; ++k) {
            int b8 = hf * 8 + 2 * k;
            int b8s = b8 ^ ((qq & 7) << 1);
            int4 v = *(const int4*)(rbase + b8s * 8);
            *(int4*)(dst + k * 8) = v;
        }
    }
}

// ---------------------------------------------------------------- GEMM2: out = AO @ Wo^T + bo (fp32 out)
__global__ void gemm_out(const bf16* __restrict__ A, const bf16* __restrict__ B,
                         const float* __restrict__ bias, float* __restrict__ C) {
    const int K = 1024, N = 1024;
    __shared__ bf16 Alds[128 * 32];
    __shared__ bf16 Blds[128 * 32];
    int t = threadIdx.x;
    int lane = t & 63;
    int wave = t >> 6;
    int wm = wave >> 1, wn = wave & 1;
    int r = lane & 15, q = lane >> 4;
    long m0 = (long)blockIdx.y * 128;
    long n0 = (long)blockIdx.x * 128;
    const bf16* Ab = A + m0 * K;
    const bf16* Bb = B + n0 * K;

    f32x4 acc[4][4] = {};

    int srow = t >> 2;
    int scol = (t & 3) << 3;

    for (int k0 = 0; k0 < K; k0 += 32) {
        __syncthreads();
        gload_lds16(Ab + (long)srow * K + k0 + scol, Alds + t * 8);
        gload_lds16(Ab + (long)(srow + 64) * K + k0 + scol, Alds + 2048 + t * 8);
        gload_lds16(Bb + (long)srow * K + k0 + scol, Blds + t * 8);
        gload_lds16(Bb + (long)(srow + 64) * K + k0 + scol, Blds + 2048 + t * 8);
        __syncthreads();

        bf16x8 af[4], bfv[4];
#pragma unroll
        for (int mi = 0; mi < 4; mi++)
            af[mi] = *(const bf16x8*)(Alds + (wm * 64 + mi * 16 + r) * 32 + q * 8);
#pragma unroll
        for (int ni = 0; ni < 4; ni++)
            bfv[ni] = *(const bf16x8*)(Blds + (wn * 64 + ni * 16 + r) * 32 + q * 8);
#pragma unroll
        for (int mi = 0; mi < 4; mi++)
#pragma unroll
            for (int ni = 0; ni < 4; ni++)
                acc[mi][ni] = MFMA16(af[mi], bfv[ni], acc[mi][ni]);
    }

#pragma unroll
    for (int ni = 0; ni < 4; ni++) {
        int n = (int)n0 + wn * 64 + ni * 16 + r;
        float bn = bias[n];
#pragma unroll
        for (int mi = 0; mi < 4; mi++) {
#pragma unroll
            for (int rr = 0; rr < 4; rr++) {
                long m = m0 + wm * 64 + mi * 16 + q * 4 + rr;
                C[m * N + n] = acc[mi][ni][rr] + bn;
            }
        }
    }
}

// ---------------------------------------------------------------- launch
extern "C" void kernel_launch(void* const* d_in, const int* in_sizes, int n_in,
                              void* d_out, int out_size, void* d_ws, size_t ws_size,
                              hipStream_t stream) {
    const float* x    = (const float*)d_in[0];
    const float* Wqkv = (const float*)d_in[1];
    const float* bqkv = (const float*)d_in[2];
    const float* Wo   = (const float*)d_in[3];
    const float* bo   = (const float*)d_in[4];
    float* out = (float*)d_out;

    char* ws = (char*)d_ws;
    bf16* Xb  = (bf16*)(ws + 0);
    bf16* Wqb = (bf16*)(ws + 16777216);
    bf16* Wob = (bf16*)(ws + 23068672);
    bf16* Qb  = (bf16*)(ws + 25165824);
    bf16* Kb  = (bf16*)(ws + 41943040);
    bf16* Vtb = (bf16*)(ws + 58720256);
    bf16* AOb = (bf16*)(ws + 75497472);

    cvt_f32_bf16<<<8192, 256, 0, stream>>>(x, Xb, 8192 * 1024 / 4);
    cvt_f32_bf16<<<3072, 256, 0, stream>>>(Wqkv, Wqb, 3072 * 1024 / 4);
    cvt_f32_bf16<<<1024, 256, 0, stream>>>(Wo, Wob, 1024 * 1024 / 4);

    gemm_qkv<<<dim3(24, 64), 256, 0, stream>>>(Xb, Wqb, bqkv, Qb, Kb, Vtb);
    attn_fwd<<<512, 512, 0, stream>>>(Qb, Kb, Vtb, AOb);
    gemm_out<<<dim3(8, 64), 256, 0, stream>>>(AOb, Wob, bo, out);
}

// Round 9
// 201.333 us; speedup vs baseline: 1.4696x; 1.0207x over previous
//
#include <hip/hip_runtime.h>
#include <hip/hip_bf16.h>

using bf16 = __hip_bfloat16;
typedef __attribute__((ext_vector_type(8))) __bf16 bf16x8;
typedef __attribute__((ext_vector_type(4))) float f32x4;
typedef __attribute__((ext_vector_type(16))) float f32x16;
typedef __attribute__((ext_vector_type(4))) unsigned u32x4;

#define MFMA16(a, b, c) __builtin_amdgcn_mfma_f32_16x16x32_bf16((a), (b), (c), 0, 0, 0)
#define MFMA32(a, b, c) __builtin_amdgcn_mfma_f32_32x32x16_bf16((a), (b), (c), 0, 0, 0)

static __device__ __forceinline__ void gload_lds16(const bf16* g, bf16* l) {
    __builtin_amdgcn_global_load_lds(
        (__attribute__((address_space(1))) void*)(bf16*)(g),
        (__attribute__((address_space(3))) void*)(l), 16, 0, 0);
}

static __device__ __forceinline__ unsigned cvtpk(float lo, float hi) {
    unsigned r;
    asm("v_cvt_pk_bf16_f32 %0, %1, %2" : "=v"(r) : "v"(lo), "v"(hi));
    return r;
}

// ---------------------------------------------------------------- convert (all 3 inputs, one launch)
__global__ void cvt_all(const float* __restrict__ x, const float* __restrict__ wq,
                        const float* __restrict__ wo,
                        bf16* __restrict__ xb, bf16* __restrict__ wqb, bf16* __restrict__ wob) {
    int b = blockIdx.x;
    const float* src;
    bf16* dst;
    long i;
    if (b < 8192)       { src = x;  dst = xb;  i = (long)b * 256 + threadIdx.x; }
    else if (b < 11264) { src = wq; dst = wqb; i = (long)(b - 8192) * 256 + threadIdx.x; }
    else                { src = wo; dst = wob; i = (long)(b - 11264) * 256 + threadIdx.x; }
    float4 v = ((const float4*)src)[i];
    bf16 t[4];
    t[0] = __float2bfloat16(v.x);
    t[1] = __float2bfloat16(v.y);
    t[2] = __float2bfloat16(v.z);
    t[3] = __float2bfloat16(v.w);
    *(uint2*)(dst + 4l * i) = *(uint2*)t;
}

// ---------------------------------------------------------------- GEMM1: qkv = x @ Wqkv^T + b, scatter to Q,K,V^T (bf16)
// 2-phase double-buffered gload_lds staging; XCD-swizzled 1D grid (1536 blocks):
// xcd = lin&7 owns m-tiles [xcd*8, xcd*8+8) -> A-strip (2MB) + B (6MB) per XCD-L2.
__global__ void gemm_qkv(const bf16* __restrict__ A, const bf16* __restrict__ B,
                         const float* __restrict__ bias,
                         bf16* __restrict__ Qo, bf16* __restrict__ Ko, bf16* __restrict__ Vt) {
    const int K = 1024;
    __shared__ bf16 Alds[2][4096];
    __shared__ bf16 Blds[2][4096];
    int t = threadIdx.x;
    int lane = t & 63;
    int wave = t >> 6;
    int wm = wave >> 1, wn = wave & 1;
    int r = lane & 15, q = lane >> 4;
    int lin = blockIdx.x;
    int xcd = lin & 7, rr_ = lin >> 3;       // rr_ in 0..191
    int mi = xcd * 8 + rr_ / 24;             // 0..63
    int ni = rr_ % 24;                       // 0..23
    long m0 = (long)mi * 128;
    long n0 = (long)ni * 128;
    const bf16* Ab = A + m0 * K;
    const bf16* Bb = B + n0 * K;

    f32x4 acc[4][4] = {};

    int srow = t >> 2;
    int scol = (t & 3) << 3;

    auto stage = [&](int buf, int k0) {
        gload_lds16(Ab + (long)srow * K + k0 + scol, Alds[buf] + t * 8);
        gload_lds16(Ab + (long)(srow + 64) * K + k0 + scol, Alds[buf] + 2048 + t * 8);
        gload_lds16(Bb + (long)srow * K + k0 + scol, Blds[buf] + t * 8);
        gload_lds16(Bb + (long)(srow + 64) * K + k0 + scol, Blds[buf] + 2048 + t * 8);
    };
    auto compute = [&](int buf) {
        bf16x8 af[4], bfv[4];
#pragma unroll
        for (int mi4 = 0; mi4 < 4; mi4++)
            af[mi4] = *(const bf16x8*)(Alds[buf] + (wm * 64 + mi4 * 16 + r) * 32 + q * 8);
#pragma unroll
        for (int ni4 = 0; ni4 < 4; ni4++)
            bfv[ni4] = *(const bf16x8*)(Blds[buf] + (wn * 64 + ni4 * 16 + r) * 32 + q * 8);
#pragma unroll
        for (int mi4 = 0; mi4 < 4; mi4++)
#pragma unroll
            for (int ni4 = 0; ni4 < 4; ni4++)
                acc[mi4][ni4] = MFMA16(af[mi4], bfv[ni4], acc[mi4][ni4]);
    };

    stage(0, 0);
    __syncthreads();                 // drains vmcnt: buf0 ready
    int cur = 0;
    for (int k0 = 32; k0 < K; k0 += 32) {
        stage(cur ^ 1, k0);          // prefetch next K-step (in flight during compute)
        compute(cur);
        __syncthreads();             // next buf ready; cur free for overwrite
        cur ^= 1;
    }
    compute(cur);

#pragma unroll
    for (int ni4 = 0; ni4 < 4; ni4++) {
        int n = (int)n0 + wn * 64 + ni4 * 16 + r;
        float bn = bias[n];
        int h = n / 192;
        int rem = n % 192;
        int part = rem >> 6;
        int d = rem & 63;
#pragma unroll
        for (int mi4 = 0; mi4 < 4; mi4++) {
#pragma unroll
            for (int rr = 0; rr < 4; rr++) {
                int m = (int)m0 + wm * 64 + mi4 * 16 + q * 4 + rr;
                int b = m >> 11;
                int row = m & 2047;
                long bh = b * 16 + h;
                bf16 bv = __float2bfloat16(acc[mi4][ni4][rr] + bn);
                if (part == 0)      Qo[(bh * 2048 + row) * 64 + d] = bv;
                else if (part == 1) Ko[(bh * 2048 + row) * 64 + d] = bv;
                else                Vt[(bh * 64 + d) * 2048 + row] = bv;
            }
        }
    }
}

// ---------------------------------------------------------------- attention
// 8 waves x 32 q = 256 q/block; KVBLK=64 double-buffered via global_load_lds.
// Swapped QK^T, in-register P (permlane32_swap), O^T accum, defer-max.

#define PACK8(S, OFF, OUTV) { \
    unsigned A0 = cvtpk(S[OFF+0], S[OFF+1]); \
    unsigned B0 = cvtpk(S[OFF+4], S[OFF+5]); \
    unsigned A1 = cvtpk(S[OFF+2], S[OFF+3]); \
    unsigned B1 = cvtpk(S[OFF+6], S[OFF+7]); \
    asm("v_permlane32_swap_b32 %0, %1" : "+v"(A0), "+v"(B0)); \
    asm("v_permlane32_swap_b32 %0, %1" : "+v"(A1), "+v"(B1)); \
    u32x4 W; W.x = A0; W.y = A1; W.z = B0; W.w = B1; \
    OUTV = __builtin_bit_cast(bf16x8, W); }

#define COMPUTE(KB, VB) do { \
    f32x16 sA = {}, sB = {}; \
    __builtin_amdgcn_s_setprio(1); \
    { \
        bf16x8 kA, kB; \
        kA = *(const bf16x8*)(KB + (0 * 64 + lane) * 8); \
        kB = *(const bf16x8*)(KB + (256 + 0 * 64 + lane) * 8); \
        sA = MFMA32(kA, qf0, sA);  sB = MFMA32(kB, qf0, sB); \
        kA = *(const bf16x8*)(KB + (1 * 64 + lane) * 8); \
        kB = *(const bf16x8*)(KB + (256 + 1 * 64 + lane) * 8); \
        sA = MFMA32(kA, qf1, sA);  sB = MFMA32(kB, qf1, sB); \
        kA = *(const bf16x8*)(KB + (2 * 64 + lane) * 8); \
        kB = *(const bf16x8*)(KB + (256 + 2 * 64 + lane) * 8); \
        sA = MFMA32(kA, qf2, sA);  sB = MFMA32(kB, qf2, sB); \
        kA = *(const bf16x8*)(KB + (3 * 64 + lane) * 8); \
        kB = *(const bf16x8*)(KB + (256 + 3 * 64 + lane) * 8); \
        sA = MFMA32(kA, qf3, sA);  sB = MFMA32(kB, qf3, sB); \
    } \
    __builtin_amdgcn_s_setprio(0); \
    float x0 = fmaxf(fmaxf(sA[0], sA[1]), fmaxf(sA[2], sA[3])); \
    float x1 = fmaxf(fmaxf(sA[4], sA[5]), fmaxf(sA[6], sA[7])); \
    float x2 = fmaxf(fmaxf(sA[8], sA[9]), fmaxf(sA[10], sA[11])); \
    float x3 = fmaxf(fmaxf(sA[12], sA[13]), fmaxf(sA[14], sA[15])); \
    float y0 = fmaxf(fmaxf(sB[0], sB[1]), fmaxf(sB[2], sB[3])); \
    float y1 = fmaxf(fmaxf(sB[4], sB[5]), fmaxf(sB[6], sB[7])); \
    float y2 = fmaxf(fmaxf(sB[8], sB[9]), fmaxf(sB[10], sB[11])); \
    float y3 = fmaxf(fmaxf(sB[12], sB[13]), fmaxf(sB[14], sB[15])); \
    float pm = fmaxf(fmaxf(fmaxf(x0, x1), fmaxf(x2, x3)), \
                     fmaxf(fmaxf(y0, y1), fmaxf(y2, y3))); \
    pm = fmaxf(pm, __shfl_xor(pm, 32)); \
    bool resc = !__all(pm <= mv + 8.0f); \
    if (resc) { \
        float mn = fmaxf(mv, pm); \
        float al = __builtin_amdgcn_exp2f((mv - mn) * C1); \
        mv = mn; \
        lv *= al; \
        _Pragma("unroll") for (int e = 0; e < 16; ++e) { o0[e] *= al; o1[e] *= al; } \
    } \
    float mc = mv * C1; \
    _Pragma("unroll") for (int e = 0; e < 16; ++e) sA[e] = __builtin_amdgcn_exp2f(sA[e] * C1 - mc); \
    _Pragma("unroll") for (int e = 0; e < 16; ++e) sB[e] = __builtin_amdgcn_exp2f(sB[e] * C1 - mc); \
    { \
        f32x16 scv = sA + sB; \
        float u0 = (scv[0] + scv[1]) + (scv[2] + scv[3]); \
        float u1 = (scv[4] + scv[5]) + (scv[6] + scv[7]); \
        float u2 = (scv[8] + scv[9]) + (scv[10] + scv[11]); \
        float u3 = (scv[12] + scv[13]) + (scv[14] + scv[15]); \
        float ts = (u0 + u1) + (u2 + u3); \
        ts += __shfl_xor(ts, 32); \
        lv += ts; \
    } \
    bf16x8 pf0, pf1, pf2, pf3; \
    PACK8(sA, 0, pf0); PACK8(sA, 8, pf1); PACK8(sB, 0, pf2); PACK8(sB, 8, pf3); \
    __builtin_amdgcn_s_setprio(1); \
    { \
        bf16x8 vA, vB; \
        vA = *(const bf16x8*)(VB + (0 * 64 + lane) * 8); \
        vB = *(const bf16x8*)(VB + (256 + 0 * 64 + lane) * 8); \
        o0 = MFMA32(vA, pf0, o0);  o1 = MFMA32(vB, pf0, o1); \
        vA = *(const bf16x8*)(VB + (1 * 64 + lane) * 8); \
        vB = *(const bf16x8*)(VB + (256 + 1 * 64 + lane) * 8); \
        o0 = MFMA32(vA, pf1, o0);  o1 = MFMA32(vB, pf1, o1); \
        vA = *(const bf16x8*)(VB + (2 * 64 + lane) * 8); \
        vB = *(const bf16x8*)(VB + (256 + 2 * 64 + lane) * 8); \
        o0 = MFMA32(vA, pf2, o0);  o1 = MFMA32(vB, pf2, o1); \
        vA = *(const bf16x8*)(VB + (3 * 64 + lane) * 8); \
        vB = *(const bf16x8*)(VB + (256 + 3 * 64 + lane) * 8); \
        o0 = MFMA32(vA, pf3, o0);  o1 = MFMA32(vB, pf3, o1); \
    } \
    __builtin_amdgcn_s_setprio(0); \
} while (0)

__global__ __launch_bounds__(512, 4) void attn_fwd(const bf16* __restrict__ Q,
                                                   const bf16* __restrict__ Kg,
                                                   const bf16* __restrict__ Vt,
                                                   bf16* __restrict__ AO) {
    __shared__ bf16 smem[16384];   // [K0 4096][V0 4096][K1 4096][V1 4096]
    bf16* K0 = smem;
    bf16* V0 = smem + 4096;
    bf16* K1 = smem + 8192;
    bf16* V1 = smem + 12288;
    const int t = threadIdx.x;
    const int lane = t & 63, wave = t >> 6;
    const int l31 = lane & 31, hi = lane >> 5;
    const int bid = blockIdx.x;
    const int xcd = bid & 7, idx = bid >> 3;
    const int bh = xcd * 8 + (idx >> 3);
    const int qt = idx & 7;
    const float C1 = 0.18033688011112042f;   // log2(e)/sqrt(64)

    bf16x8 qf0, qf1, qf2, qf3;
    {
        const bf16* Qb = Q + ((long)bh * 2048 + qt * 256 + wave * 32 + l31) * 64 + hi * 8;
        qf0 = *(const bf16x8*)(Qb + 0);
        qf1 = *(const bf16x8*)(Qb + 16);
        qf2 = *(const bf16x8*)(Qb + 32);
        qf3 = *(const bf16x8*)(Qb + 48);
    }

    const bf16* Kh = Kg + (long)bh * 2048 * 64;
    const bf16* Vh = Vt + (long)bh * 64 * 2048;

    const int sr = ((t >> 8) << 5) + (t & 31);          // 0..63
    const int sc = ((t >> 6) & 3) * 16 + ((t >> 5) & 1) * 8;

    f32x16 o0 = {}, o1 = {};
    float mv = -1e30f, lv = 0.f;

    auto issue_stage = [&](bf16* Kb, bf16* Vb, int kv0) {
        gload_lds16(Kh + (long)(kv0 + sr) * 64 + sc, Kb + t * 8);
        gload_lds16(Vh + (long)sr * 2048 + kv0 + sc, Vb + t * 8);
    };

    issue_stage(K0, V0, 0);
    __syncthreads();

    for (int kv0 = 0;; kv0 += 128) {
        issue_stage(K1, V1, kv0 + 64);
        COMPUTE(K0, V0);
        __syncthreads();
        if (kv0 + 128 < 2048) issue_stage(K0, V0, kv0 + 128);
        COMPUTE(K1, V1);
        if (kv0 + 128 >= 2048) break;
        __syncthreads();
    }

    // ---- epilogue: O^T -> LDS transpose -> coalesced global stores
    long bb = bh >> 4, hh = bh & 15;
    __syncthreads();
    float il = 1.f / lv;
    char* wbase = (char*)smem + wave * 4096 + l31 * 128;
#pragma unroll
    for (int j = 0; j < 4; ++j) {
        unsigned wlo = cvtpk(o0[4 * j] * il, o0[4 * j + 1] * il);
        unsigned whi = cvtpk(o0[4 * j + 2] * il, o0[4 * j + 3] * il);
        int b8 = 2 * j + hi;
        int b8s = b8 ^ ((l31 & 7) << 1);
        uint2 val; val.x = wlo; val.y = whi;
        *(uint2*)(wbase + b8s * 8) = val;
    }
#pragma unroll
    for (int j = 0; j < 4; ++j) {
        unsigned wlo = cvtpk(o1[4 * j] * il, o1[4 * j + 1] * il);
        unsigned whi = cvtpk(o1[4 * j + 2] * il, o1[4 * j + 3] * il);
        int b8 = 8 + 2 * j + hi;
        int b8s = b8 ^ ((l31 & 7) << 1);
        uint2 val; val.x = wlo; val.y = whi;
        *(uint2*)(wbase + b8s * 8) = val;
    }
    __syncthreads();
    {
        int rid = t >> 1, hf = t & 1;
        int wv = rid >> 5, qq = rid & 31;
        long orow = (long)qt * 256 + wv * 32 + qq;
        const char* rbase = (const char*)smem + wv * 4096 + qq * 128;
        bf16* dst = AO + (bb * 2048 + orow) * 1024 + hh * 64 + hf * 32;
#pragma unroll
        for (int k = 0; k < 4; ++k) {
            int b8 = hf * 8 + 2 * k;
            int b8s = b8 ^ ((qq & 7) << 1);
            int4 v = *(const int4*)(rbase + b8s * 8);
            *(int4*)(dst + k * 8) = v;
        }
    }
}

// ---------------------------------------------------------------- GEMM2: out = AO @ Wo^T + bo (fp32 out)
// 2-phase double-buffered; XCD-swizzled 1D grid (512 blocks): xcd owns m-strip.
__global__ void gemm_out(const bf16* __restrict__ A, const bf16* __restrict__ B,
                         const float* __restrict__ bias, float* __restrict__ C) {
    const int K = 1024, N = 1024;
    __shared__ bf16 Alds[2][4096];
    __shared__ bf16 Blds[2][4096];
    int t = threadIdx.x;
    int lane = t & 63;
    int wave = t >> 6;
    int wm = wave >> 1, wn = wave & 1;
    int r = lane & 15, q = lane >> 4;
    int lin = blockIdx.x;
    int xcd = lin & 7, rr_ = lin >> 3;       // 0..63
    int mi = xcd * 8 + (rr_ >> 3);           // 0..63
    int ni = rr_ & 7;                        // 0..7
    long m0 = (long)mi * 128;
    long n0 = (long)ni * 128;
    const bf16* Ab = A + m0 * K;
    const bf16* Bb = B + n0 * K;

    f32x4 acc[4][4] = {};

    int srow = t >> 2;
    int scol = (t & 3) << 3;

    auto stage = [&](int buf, int k0) {
        gload_lds16(Ab + (long)srow * K + k0 + scol, Alds[buf] + t * 8);
        gload_lds16(Ab + (long)(srow + 64) * K + k0 + scol, Alds[buf] + 2048 + t * 8);
        gload_lds16(Bb + (long)srow * K + k0 + scol, Blds[buf] + t * 8);
        gload_lds16(Bb + (long)(srow + 64) * K + k0 + scol, Blds[buf] + 2048 + t * 8);
    };
    auto compute = [&](int buf) {
        bf16x8 af[4], bfv[4];
#pragma unroll
        for (int mi4 = 0; mi4 < 4; mi4++)
            af[mi4] = *(const bf16x8*)(Alds[buf] + (wm * 64 + mi4 * 16 + r) * 32 + q * 8);
#pragma unroll
        for (int ni4 = 0; ni4 < 4; ni4++)
            bfv[ni4] = *(const bf16x8*)(Blds[buf] + (wn * 64 + ni4 * 16 + r) * 32 + q * 8);
#pragma unroll
        for (int mi4 = 0; mi4 < 4; mi4++)
#pragma unroll
            for (int ni4 = 0; ni4 < 4; ni4++)
                acc[mi4][ni4] = MFMA16(af[mi4], bfv[ni4], acc[mi4][ni4]);
    };

    stage(0, 0);
    __syncthreads();
    int cur = 0;
    for (int k0 = 32; k0 < K; k0 += 32) {
        stage(cur ^ 1, k0);
        compute(cur);
        __syncthreads();
        cur ^= 1;
    }
    compute(cur);

#pragma unroll
    for (int ni4 = 0; ni4 < 4; ni4++) {
        int n = (int)n0 + wn * 64 + ni4 * 16 + r;
        float bn = bias[n];
#pragma unroll
        for (int mi4 = 0; mi4 < 4; mi4++) {
#pragma unroll
            for (int rr = 0; rr < 4; rr++) {
                long m = m0 + wm * 64 + mi4 * 16 + q * 4 + rr;
                C[m * N + n] = acc[mi4][ni4][rr] + bn;
            }
        }
    }
}

// ---------------------------------------------------------------- launch
extern "C" void kernel_launch(void* const* d_in, const int* in_sizes, int n_in,
                              void* d_out, int out_size, void* d_ws, size_t ws_size,
                              hipStream_t stream) {
    const float* x    = (const float*)d_in[0];
    const float* Wqkv = (const float*)d_in[1];
    const float* bqkv = (const float*)d_in[2];
    const float* Wo   = (const float*)d_in[3];
    const float* bo   = (const float*)d_in[4];
    float* out = (float*)d_out;

    char* ws = (char*)d_ws;
    bf16* Xb  = (bf16*)(ws + 0);
    bf16* Wqb = (bf16*)(ws + 16777216);
    bf16* Wob = (bf16*)(ws + 23068672);
    bf16* Qb  = (bf16*)(ws + 25165824);
    bf16* Kb  = (bf16*)(ws + 41943040);
    bf16* Vtb = (bf16*)(ws + 58720256);
    bf16* AOb = (bf16*)(ws + 75497472);

    cvt_all<<<12288, 256, 0, stream>>>(x, Wqkv, Wo, Xb, Wqb, Wob);

    gemm_qkv<<<1536, 256, 0, stream>>>(Xb, Wqb, bqkv, Qb, Kb, Vtb);
    attn_fwd<<<512, 512, 0, stream>>>(Qb, Kb, Vtb, AOb);
    gemm_out<<<512, 256, 0, stream>>>(AOb, Wob, bo, out);
}